// Round 1
// baseline (4472.829 us; speedup 1.0000x reference)
//
#include <hip/hip_runtime.h>
#include <hip/hip_bf16.h>

#define N_NODES 50000
#define N_EDGES 800000
#define N_GRAPHS 64
#define IN_DIM 384
#define HID 128
#define MLP_HID 64

// ---------------------------------------------------------------- degree
__global__ __launch_bounds__(256) void deg_kernel(const int* __restrict__ dst,
                                                  float* __restrict__ deg, int E) {
    int t = blockIdx.x * 256 + threadIdx.x;
    if (t < E) atomicAdd(&deg[dst[t]], 1.0f);
}

__global__ __launch_bounds__(256) void dis_kernel(const float* __restrict__ deg,
                                                  float* __restrict__ dis, int n) {
    int t = blockIdx.x * 256 + threadIdx.x;
    if (t < n) dis[t] = rsqrtf(deg[t] + 1.0f);
}

// ---------------------------------------------------------------- GEMM  H = (relu?)X @ W
// X: [M, K] row-major, W: [K, 128] row-major, H: [M, 128]
// tile: 64 rows x 128 cols per block, 256 threads, K-step 32
template <int K, bool RELU_IN>
__global__ __launch_bounds__(256) void gemm_kernel(const float* __restrict__ X,
                                                   const float* __restrict__ W,
                                                   float* __restrict__ H, int M) {
    __shared__ float Xs[64][32];
    __shared__ float Ws[32][128];
    const int tid = threadIdx.x;
    const int row0 = blockIdx.x * 64;
    const int tn = tid & 31;   // col group: 4 cols
    const int tm = tid >> 5;   // row group: 8 rows
    float acc[8][4] = {};

    for (int k0 = 0; k0 < K; k0 += 32) {
        // stage X tile: 64 x 32
        {
            const int r = tid >> 3;          // 0..31
            const int kq = (tid & 7) * 4;    // 0..28 step 4
#pragma unroll
            for (int rr = 0; rr < 2; ++rr) {
                const int row = row0 + r + rr * 32;
                float4 v = make_float4(0.f, 0.f, 0.f, 0.f);
                if (row < M) v = *reinterpret_cast<const float4*>(&X[row * K + k0 + kq]);
                if (RELU_IN) {
                    v.x = fmaxf(v.x, 0.f); v.y = fmaxf(v.y, 0.f);
                    v.z = fmaxf(v.z, 0.f); v.w = fmaxf(v.w, 0.f);
                }
                *reinterpret_cast<float4*>(&Xs[r + rr * 32][kq]) = v;
            }
        }
        // stage W tile: 32 x 128
        {
            const int kr = tid >> 3;         // 0..31
#pragma unroll
            for (int i = 0; i < 4; ++i) {
                const int c4 = (tid & 7) + 8 * i;   // 0..31
                *reinterpret_cast<float4*>(&Ws[kr][c4 * 4]) =
                    *reinterpret_cast<const float4*>(&W[(k0 + kr) * 128 + c4 * 4]);
            }
        }
        __syncthreads();
#pragma unroll
        for (int kk = 0; kk < 32; ++kk) {
            float b[4];
            *reinterpret_cast<float4*>(b) = *reinterpret_cast<float4*>(&Ws[kk][tn * 4]);
#pragma unroll
            for (int m = 0; m < 8; ++m) {
                const float a = Xs[tm * 8 + m][kk];
                acc[m][0] = fmaf(a, b[0], acc[m][0]);
                acc[m][1] = fmaf(a, b[1], acc[m][1]);
                acc[m][2] = fmaf(a, b[2], acc[m][2]);
                acc[m][3] = fmaf(a, b[3], acc[m][3]);
            }
        }
        __syncthreads();
    }
#pragma unroll
    for (int m = 0; m < 8; ++m) {
        const int row = row0 + tm * 8 + m;
        if (row < M) {
            float4 v = make_float4(acc[m][0], acc[m][1], acc[m][2], acc[m][3]);
            *reinterpret_cast<float4*>(&H[row * 128 + tn * 4]) = v;
        }
    }
}

// ---------------------------------------------------------------- AGG init: AGG = H*dis^2 + b
__global__ __launch_bounds__(256) void init_agg_kernel(const float* __restrict__ H,
                                                       const float* __restrict__ dis,
                                                       const float* __restrict__ b,
                                                       float* __restrict__ AGG, int n) {
    int t = blockIdx.x * 256 + threadIdx.x;   // n*32 threads, 4 feats each
    int node = t >> 5;
    if (node >= n) return;
    int lane = t & 31;
    float d = dis[node];
    float dd = d * d;
    float4 h = *reinterpret_cast<const float4*>(&H[node * 128 + lane * 4]);
    float4 bb = *reinterpret_cast<const float4*>(&b[lane * 4]);
    float4 o;
    o.x = fmaf(h.x, dd, bb.x);
    o.y = fmaf(h.y, dd, bb.y);
    o.z = fmaf(h.z, dd, bb.z);
    o.w = fmaf(h.w, dd, bb.w);
    *reinterpret_cast<float4*>(&AGG[node * 128 + lane * 4]) = o;
}

// ---------------------------------------------------------------- edge scatter
// AGG[dst] += H[src] * dis[src]*dis[dst];  32 threads per edge, float4 each
__global__ __launch_bounds__(256) void scatter_kernel(const int* __restrict__ ei,
                                                      const float* __restrict__ H,
                                                      const float* __restrict__ dis,
                                                      float* __restrict__ AGG, int E) {
    int t = blockIdx.x * 256 + threadIdx.x;
    int e = t >> 5;
    if (e >= E) return;
    int lane = t & 31;
    int src = ei[e];
    int dst = ei[E + e];
    float en = dis[src] * dis[dst];
    float4 v = *reinterpret_cast<const float4*>(&H[src * 128 + lane * 4]);
    float* o = &AGG[dst * 128 + lane * 4];
    atomicAdd(o + 0, v.x * en);
    atomicAdd(o + 1, v.y * en);
    atomicAdd(o + 2, v.z * en);
    atomicAdd(o + 3, v.w * en);
}

// ---------------------------------------------------------------- pool (mean of relu(AGG) per graph)
__global__ __launch_bounds__(256) void pool_kernel(const float* __restrict__ AGG,
                                                   const int* __restrict__ batch,
                                                   float* __restrict__ pooled, int n) {
    const int g = blockIdx.x;
    // lower_bound(batch, g)
    int lo = 0, hi = n;
    while (lo < hi) { int mid = (lo + hi) >> 1; if (batch[mid] < g) lo = mid + 1; else hi = mid; }
    const int start = lo;
    hi = n;
    while (lo < hi) { int mid = (lo + hi) >> 1; if (batch[mid] < g + 1) lo = mid + 1; else hi = mid; }
    const int end = lo;

    const int f = threadIdx.x & 127;
    const int h = threadIdx.x >> 7;
    float s = 0.f;
    for (int i = start + h; i < end; i += 2) s += fmaxf(AGG[i * 128 + f], 0.f);
    __shared__ float sh[2][128];
    sh[h][f] = s;
    __syncthreads();
    if (h == 0) {
        float tot = sh[0][f] + sh[1][f];
        float cnt = (float)(end - start);
        pooled[g * 128 + f] = tot / fmaxf(cnt, 1.f);
    }
}

// ---------------------------------------------------------------- MLP head
__global__ __launch_bounds__(256) void mlp_kernel(const float* __restrict__ pooled,
                                                  const float* __restrict__ Wm1,
                                                  const float* __restrict__ bm1,
                                                  const float* __restrict__ Wm2,
                                                  const float* __restrict__ bm2,
                                                  float* __restrict__ out) {
    __shared__ float P[N_GRAPHS][HID];
    __shared__ float Wl[HID][MLP_HID];
    const int tid = threadIdx.x;
    for (int i = tid; i < N_GRAPHS * HID; i += 256) P[i >> 7][i & 127] = pooled[i];
    for (int i = tid; i < HID * MLP_HID; i += 256) Wl[i >> 6][i & 63] = Wm1[i];
    __syncthreads();
    const int g = tid >> 2;
    const int jb = tid & 3;
    float part = 0.f;
#pragma unroll
    for (int jj = 0; jj < 16; ++jj) {
        const int j = jb * 16 + jj;
        float z = bm1[j];
        for (int k = 0; k < HID; ++k) z = fmaf(P[g][k], Wl[k][j], z);
        z = fmaxf(z, 0.f);
        part = fmaf(z, Wm2[j], part);
    }
    part += __shfl_xor(part, 1);
    part += __shfl_xor(part, 2);
    if (jb == 0) out[g] = part + bm2[0];
}

extern "C" void kernel_launch(void* const* d_in, const int* in_sizes, int n_in,
                              void* d_out, int out_size, void* d_ws, size_t ws_size,
                              hipStream_t stream) {
    const float* x   = (const float*)d_in[0];
    const int*   ei  = (const int*)d_in[1];
    const int*   bat = (const int*)d_in[2];
    const float* W1  = (const float*)d_in[3];
    const float* b1  = (const float*)d_in[4];
    const float* W2  = (const float*)d_in[5];
    const float* b2  = (const float*)d_in[6];
    const float* W3  = (const float*)d_in[7];
    const float* b3  = (const float*)d_in[8];
    const float* Wm1 = (const float*)d_in[9];
    const float* bm1 = (const float*)d_in[10];
    const float* Wm2 = (const float*)d_in[11];
    const float* bm2 = (const float*)d_in[12];
    float* out = (float*)d_out;

    float* ws     = (float*)d_ws;
    float* deg    = ws;                       // 50000
    float* dis    = ws + 50048;               // 50000
    float* H      = ws + 100096;              // 6.4M
    float* AGG    = H + N_NODES * HID;        // 6.4M
    float* pooled = AGG + N_NODES * HID;      // 8192

    hipMemsetAsync(deg, 0, N_NODES * sizeof(float), stream);

    deg_kernel<<<(N_EDGES + 255) / 256, 256, 0, stream>>>(ei + N_EDGES, deg, N_EDGES);
    dis_kernel<<<(N_NODES + 255) / 256, 256, 0, stream>>>(deg, dis, N_NODES);

    const int gemm_blocks = (N_NODES + 63) / 64;
    const int agg_blocks  = (N_NODES * 32 + 255) / 256;
    const int sc_blocks   = (N_EDGES * 32 + 255) / 256;

    // layer 1
    gemm_kernel<IN_DIM, false><<<gemm_blocks, 256, 0, stream>>>(x, W1, H, N_NODES);
    init_agg_kernel<<<agg_blocks, 256, 0, stream>>>(H, dis, b1, AGG, N_NODES);
    scatter_kernel<<<sc_blocks, 256, 0, stream>>>(ei, H, dis, AGG, N_EDGES);
    // layer 2
    gemm_kernel<HID, true><<<gemm_blocks, 256, 0, stream>>>(AGG, W2, H, N_NODES);
    init_agg_kernel<<<agg_blocks, 256, 0, stream>>>(H, dis, b2, AGG, N_NODES);
    scatter_kernel<<<sc_blocks, 256, 0, stream>>>(ei, H, dis, AGG, N_EDGES);
    // layer 3
    gemm_kernel<HID, true><<<gemm_blocks, 256, 0, stream>>>(AGG, W3, H, N_NODES);
    init_agg_kernel<<<agg_blocks, 256, 0, stream>>>(H, dis, b3, AGG, N_NODES);
    scatter_kernel<<<sc_blocks, 256, 0, stream>>>(ei, H, dis, AGG, N_EDGES);

    pool_kernel<<<N_GRAPHS, 256, 0, stream>>>(AGG, bat, pooled, N_NODES);
    mlp_kernel<<<1, 256, 0, stream>>>(pooled, Wm1, bm1, Wm2, bm2, out);
}

// Round 2
// 809.613 us; speedup vs baseline: 5.5247x; 5.5247x over previous
//
#include <hip/hip_runtime.h>
#include <hip/hip_bf16.h>

#define N_NODES 50000
#define N_EDGES 800000
#define N_GRAPHS 64
#define IN_DIM 384
#define HID 128
#define MLP_HID 64

// ---------------------------------------------------------------- degree count (int)
__global__ __launch_bounds__(256) void count_kernel(const int* __restrict__ dst,
                                                    int* __restrict__ cnt, int E) {
    int t = blockIdx.x * 256 + threadIdx.x;
    if (t < E) atomicAdd(&cnt[dst[t]], 1);
}

// ---------------------------------------------------------------- scan: counts -> row_ptr,
// cursor init, dis = rsqrt(deg+1). Single block, 1024 threads, 49 elems/thread.
__global__ __launch_bounds__(1024) void scan_kernel(const int* __restrict__ cnt,
                                                    int* __restrict__ rowptr,
                                                    int* __restrict__ cursor,
                                                    float* __restrict__ dis) {
    __shared__ int sh[1024];
    const int t = threadIdx.x;
    const int beg = t * 49;
    const int end = min(beg + 49, N_NODES);
    int s = 0;
    for (int i = beg; i < end; ++i) s += cnt[i];
    sh[t] = s;
    __syncthreads();
    for (int off = 1; off < 1024; off <<= 1) {
        int v = 0;
        if (t >= off) v = sh[t - off];
        __syncthreads();
        if (t >= off) sh[t] += v;
        __syncthreads();
    }
    int run = sh[t] - s;  // exclusive prefix of this chunk
    for (int i = beg; i < end; ++i) {
        int c = cnt[i];
        rowptr[i] = run;
        cursor[i] = run;
        dis[i] = rsqrtf((float)c + 1.0f);
        run += c;
    }
    if (t == 1023) rowptr[N_NODES] = sh[1023];
}

// ---------------------------------------------------------------- CSR fill
__global__ __launch_bounds__(256) void fill_kernel(const int* __restrict__ ei,
                                                   int* __restrict__ cursor,
                                                   int* __restrict__ csr, int E) {
    int e = blockIdx.x * 256 + threadIdx.x;
    if (e >= E) return;
    int s = ei[e];
    int d = ei[E + e];
    int pos = atomicAdd(&cursor[d], 1);
    csr[pos] = s;
}

// ---------------------------------------------------------------- GEMM  H = (relu?)X @ W
// X: [M, K] row-major, W: [K, 128] row-major, H: [M, 128]
template <int K, bool RELU_IN>
__global__ __launch_bounds__(256) void gemm_kernel(const float* __restrict__ X,
                                                   const float* __restrict__ W,
                                                   float* __restrict__ H, int M) {
    __shared__ float Xs[64][32];
    __shared__ float Ws[32][128];
    const int tid = threadIdx.x;
    const int row0 = blockIdx.x * 64;
    const int tn = tid & 31;
    const int tm = tid >> 5;
    float acc[8][4] = {};

    for (int k0 = 0; k0 < K; k0 += 32) {
        {
            const int r = tid >> 3;
            const int kq = (tid & 7) * 4;
#pragma unroll
            for (int rr = 0; rr < 2; ++rr) {
                const int row = row0 + r + rr * 32;
                float4 v = make_float4(0.f, 0.f, 0.f, 0.f);
                if (row < M) v = *reinterpret_cast<const float4*>(&X[row * K + k0 + kq]);
                if (RELU_IN) {
                    v.x = fmaxf(v.x, 0.f); v.y = fmaxf(v.y, 0.f);
                    v.z = fmaxf(v.z, 0.f); v.w = fmaxf(v.w, 0.f);
                }
                *reinterpret_cast<float4*>(&Xs[r + rr * 32][kq]) = v;
            }
        }
        {
            const int kr = tid >> 3;
#pragma unroll
            for (int i = 0; i < 4; ++i) {
                const int c4 = (tid & 7) + 8 * i;
                *reinterpret_cast<float4*>(&Ws[kr][c4 * 4]) =
                    *reinterpret_cast<const float4*>(&W[(k0 + kr) * 128 + c4 * 4]);
            }
        }
        __syncthreads();
#pragma unroll
        for (int kk = 0; kk < 32; ++kk) {
            float b[4];
            *reinterpret_cast<float4*>(b) = *reinterpret_cast<float4*>(&Ws[kk][tn * 4]);
#pragma unroll
            for (int m = 0; m < 8; ++m) {
                const float a = Xs[tm * 8 + m][kk];
                acc[m][0] = fmaf(a, b[0], acc[m][0]);
                acc[m][1] = fmaf(a, b[1], acc[m][1]);
                acc[m][2] = fmaf(a, b[2], acc[m][2]);
                acc[m][3] = fmaf(a, b[3], acc[m][3]);
            }
        }
        __syncthreads();
    }
#pragma unroll
    for (int m = 0; m < 8; ++m) {
        const int row = row0 + tm * 8 + m;
        if (row < M) {
            float4 v = make_float4(acc[m][0], acc[m][1], acc[m][2], acc[m][3]);
            *reinterpret_cast<float4*>(&H[row * 128 + tn * 4]) = v;
        }
    }
}

// ---------------------------------------------------------------- gather (fused init + aggregate)
// AGG[n] = b + H[n]*dis[n]^2 + sum_{s in in(n)} H[s]*dis[s]*dis[n]
__global__ __launch_bounds__(256) void gather_kernel(const int* __restrict__ rowptr,
                                                     const int* __restrict__ csr,
                                                     const float* __restrict__ H,
                                                     const float* __restrict__ dis,
                                                     const float* __restrict__ b,
                                                     float* __restrict__ AGG, int n) {
    int t = blockIdx.x * 256 + threadIdx.x;
    int node = t >> 5;
    if (node >= n) return;
    int lane = t & 31;
    const int beg = rowptr[node];
    const int end = rowptr[node + 1];
    const float d = dis[node];

    float4 acc;
    {
        float4 h = *reinterpret_cast<const float4*>(&H[node * 128 + lane * 4]);
        float4 bb = *reinterpret_cast<const float4*>(&b[lane * 4]);
        const float dd = d * d;
        acc.x = fmaf(h.x, dd, bb.x);
        acc.y = fmaf(h.y, dd, bb.y);
        acc.z = fmaf(h.z, dd, bb.z);
        acc.w = fmaf(h.w, dd, bb.w);
    }
    int i = beg;
    for (; i + 2 <= end; i += 2) {
        const int s0 = csr[i];
        const int s1 = csr[i + 1];
        const float e0 = dis[s0] * d;
        const float e1 = dis[s1] * d;
        float4 v0 = *reinterpret_cast<const float4*>(&H[s0 * 128 + lane * 4]);
        float4 v1 = *reinterpret_cast<const float4*>(&H[s1 * 128 + lane * 4]);
        acc.x = fmaf(v0.x, e0, acc.x);
        acc.y = fmaf(v0.y, e0, acc.y);
        acc.z = fmaf(v0.z, e0, acc.z);
        acc.w = fmaf(v0.w, e0, acc.w);
        acc.x = fmaf(v1.x, e1, acc.x);
        acc.y = fmaf(v1.y, e1, acc.y);
        acc.z = fmaf(v1.z, e1, acc.z);
        acc.w = fmaf(v1.w, e1, acc.w);
    }
    if (i < end) {
        const int s0 = csr[i];
        const float e0 = dis[s0] * d;
        float4 v0 = *reinterpret_cast<const float4*>(&H[s0 * 128 + lane * 4]);
        acc.x = fmaf(v0.x, e0, acc.x);
        acc.y = fmaf(v0.y, e0, acc.y);
        acc.z = fmaf(v0.z, e0, acc.z);
        acc.w = fmaf(v0.w, e0, acc.w);
    }
    *reinterpret_cast<float4*>(&AGG[node * 128 + lane * 4]) = acc;
}

// ---------------------------------------------------------------- pool (mean of relu(AGG) per graph)
__global__ __launch_bounds__(256) void pool_kernel(const float* __restrict__ AGG,
                                                   const int* __restrict__ batch,
                                                   float* __restrict__ pooled, int n) {
    const int g = blockIdx.x;
    int lo = 0, hi = n;
    while (lo < hi) { int mid = (lo + hi) >> 1; if (batch[mid] < g) lo = mid + 1; else hi = mid; }
    const int start = lo;
    hi = n;
    while (lo < hi) { int mid = (lo + hi) >> 1; if (batch[mid] < g + 1) lo = mid + 1; else hi = mid; }
    const int end = lo;

    const int f = threadIdx.x & 127;
    const int h = threadIdx.x >> 7;
    float s = 0.f;
    for (int i = start + h; i < end; i += 2) s += fmaxf(AGG[i * 128 + f], 0.f);
    __shared__ float sh[2][128];
    sh[h][f] = s;
    __syncthreads();
    if (h == 0) {
        float tot = sh[0][f] + sh[1][f];
        float cnt = (float)(end - start);
        pooled[g * 128 + f] = tot / fmaxf(cnt, 1.f);
    }
}

// ---------------------------------------------------------------- MLP head
__global__ __launch_bounds__(256) void mlp_kernel(const float* __restrict__ pooled,
                                                  const float* __restrict__ Wm1,
                                                  const float* __restrict__ bm1,
                                                  const float* __restrict__ Wm2,
                                                  const float* __restrict__ bm2,
                                                  float* __restrict__ out) {
    __shared__ float P[N_GRAPHS][HID];
    __shared__ float Wl[HID][MLP_HID];
    const int tid = threadIdx.x;
    for (int i = tid; i < N_GRAPHS * HID; i += 256) P[i >> 7][i & 127] = pooled[i];
    for (int i = tid; i < HID * MLP_HID; i += 256) Wl[i >> 6][i & 63] = Wm1[i];
    __syncthreads();
    const int g = tid >> 2;
    const int jb = tid & 3;
    float part = 0.f;
#pragma unroll
    for (int jj = 0; jj < 16; ++jj) {
        const int j = jb * 16 + jj;
        float z = bm1[j];
        for (int k = 0; k < HID; ++k) z = fmaf(P[g][k], Wl[k][j], z);
        z = fmaxf(z, 0.f);
        part = fmaf(z, Wm2[j], part);
    }
    part += __shfl_xor(part, 1);
    part += __shfl_xor(part, 2);
    if (jb == 0) out[g] = part + bm2[0];
}

extern "C" void kernel_launch(void* const* d_in, const int* in_sizes, int n_in,
                              void* d_out, int out_size, void* d_ws, size_t ws_size,
                              hipStream_t stream) {
    const float* x   = (const float*)d_in[0];
    const int*   ei  = (const int*)d_in[1];
    const int*   bat = (const int*)d_in[2];
    const float* W1  = (const float*)d_in[3];
    const float* b1  = (const float*)d_in[4];
    const float* W2  = (const float*)d_in[5];
    const float* b2  = (const float*)d_in[6];
    const float* W3  = (const float*)d_in[7];
    const float* b3  = (const float*)d_in[8];
    const float* Wm1 = (const float*)d_in[9];
    const float* bm1 = (const float*)d_in[10];
    const float* Wm2 = (const float*)d_in[11];
    const float* bm2 = (const float*)d_in[12];
    float* out = (float*)d_out;

    int*   cnt    = (int*)d_ws;                 // 50000
    int*   cursor = cnt + 50048;                // 50000
    int*   rowptr = cursor + 50048;             // 50001
    int*   csr    = rowptr + 50056;             // 800000
    float* dis    = (float*)(csr + 800000);     // 50000
    float* H      = dis + 50048;                // 6.4M
    float* AGG    = H + N_NODES * HID;          // 6.4M
    float* pooled = AGG + N_NODES * HID;        // 8192

    hipMemsetAsync(cnt, 0, N_NODES * sizeof(int), stream);

    count_kernel<<<(N_EDGES + 255) / 256, 256, 0, stream>>>(ei + N_EDGES, cnt, N_EDGES);
    scan_kernel<<<1, 1024, 0, stream>>>(cnt, rowptr, cursor, dis);
    fill_kernel<<<(N_EDGES + 255) / 256, 256, 0, stream>>>(ei, cursor, csr, N_EDGES);

    const int gemm_blocks = (N_NODES + 63) / 64;
    const int gat_blocks  = (N_NODES * 32 + 255) / 256;

    // layer 1
    gemm_kernel<IN_DIM, false><<<gemm_blocks, 256, 0, stream>>>(x, W1, H, N_NODES);
    gather_kernel<<<gat_blocks, 256, 0, stream>>>(rowptr, csr, H, dis, b1, AGG, N_NODES);
    // layer 2
    gemm_kernel<HID, true><<<gemm_blocks, 256, 0, stream>>>(AGG, W2, H, N_NODES);
    gather_kernel<<<gat_blocks, 256, 0, stream>>>(rowptr, csr, H, dis, b2, AGG, N_NODES);
    // layer 3
    gemm_kernel<HID, true><<<gemm_blocks, 256, 0, stream>>>(AGG, W3, H, N_NODES);
    gather_kernel<<<gat_blocks, 256, 0, stream>>>(rowptr, csr, H, dis, b3, AGG, N_NODES);

    pool_kernel<<<N_GRAPHS, 256, 0, stream>>>(AGG, bat, pooled, N_NODES);
    mlp_kernel<<<1, 256, 0, stream>>>(pooled, Wm1, bm1, Wm2, bm2, out);
}

// Round 3
// 684.469 us; speedup vs baseline: 6.5347x; 1.1828x over previous
//
#include <hip/hip_runtime.h>
#include <hip/hip_bf16.h>

#define N_NODES 50000
#define N_EDGES 800000
#define N_GRAPHS 64
#define IN_DIM 384
#define HID 128
#define MLP_HID 64

#define SCAN_BLOCKS ((N_NODES + 255) / 256)   // 196

// ---------------------------------------------------------------- degree count (int)
__global__ __launch_bounds__(256) void count_kernel(const int* __restrict__ dst,
                                                    int* __restrict__ cnt, int E) {
    int t = blockIdx.x * 256 + threadIdx.x;
    if (t < E) atomicAdd(&cnt[dst[t]], 1);
}

// ---------------------------------------------------------------- scan pass 1: block sums
__global__ __launch_bounds__(256) void bsum_kernel(const int* __restrict__ cnt,
                                                   int* __restrict__ bsum) {
    __shared__ int sh[256];
    const int t = threadIdx.x;
    const int i = blockIdx.x * 256 + t;
    sh[t] = (i < N_NODES) ? cnt[i] : 0;
    __syncthreads();
#pragma unroll
    for (int off = 128; off > 0; off >>= 1) {
        if (t < off) sh[t] += sh[t + off];
        __syncthreads();
    }
    if (t == 0) bsum[blockIdx.x] = sh[0];
}

// ---------------------------------------------------------------- scan pass 2: scan block sums
__global__ __launch_bounds__(256) void bscan_kernel(const int* __restrict__ bsum,
                                                    int* __restrict__ boff,
                                                    int* __restrict__ rowptr) {
    __shared__ int sh[256];
    const int t = threadIdx.x;
    int v = (t < SCAN_BLOCKS) ? bsum[t] : 0;
    sh[t] = v;
    __syncthreads();
#pragma unroll
    for (int off = 1; off < 256; off <<= 1) {
        int u = 0;
        if (t >= off) u = sh[t - off];
        __syncthreads();
        if (t >= off) sh[t] += u;
        __syncthreads();
    }
    if (t < SCAN_BLOCKS) boff[t] = sh[t] - v;   // exclusive
    if (t == 255) rowptr[N_NODES] = sh[255];    // total
}

// ---------------------------------------------------------------- scan pass 3: final
__global__ __launch_bounds__(256) void final_scan_kernel(const int* __restrict__ cnt,
                                                         const int* __restrict__ boff,
                                                         int* __restrict__ rowptr,
                                                         int* __restrict__ cursor,
                                                         float* __restrict__ dis) {
    __shared__ int sh[256];
    const int t = threadIdx.x;
    const int i = blockIdx.x * 256 + t;
    const int c = (i < N_NODES) ? cnt[i] : 0;
    sh[t] = c;
    __syncthreads();
#pragma unroll
    for (int off = 1; off < 256; off <<= 1) {
        int u = 0;
        if (t >= off) u = sh[t - off];
        __syncthreads();
        if (t >= off) sh[t] += u;
        __syncthreads();
    }
    if (i < N_NODES) {
        const int pos = boff[blockIdx.x] + sh[t] - c;   // exclusive prefix
        rowptr[i] = pos;
        cursor[i] = pos;
        dis[i] = rsqrtf((float)c + 1.0f);
    }
}

// ---------------------------------------------------------------- CSR fill
__global__ __launch_bounds__(256) void fill_kernel(const int* __restrict__ ei,
                                                   int* __restrict__ cursor,
                                                   int* __restrict__ csr, int E) {
    int e = blockIdx.x * 256 + threadIdx.x;
    if (e >= E) return;
    int s = ei[e];
    int d = ei[E + e];
    int pos = atomicAdd(&cursor[d], 1);
    csr[pos] = s;
}

// ---------------------------------------------------------------- GEMM  H = (relu?)X @ W
template <int K, bool RELU_IN>
__global__ __launch_bounds__(256) void gemm_kernel(const float* __restrict__ X,
                                                   const float* __restrict__ W,
                                                   float* __restrict__ H, int M) {
    __shared__ float Xs[64][32];
    __shared__ float Ws[32][128];
    const int tid = threadIdx.x;
    const int row0 = blockIdx.x * 64;
    const int tn = tid & 31;
    const int tm = tid >> 5;
    float acc[8][4] = {};

    for (int k0 = 0; k0 < K; k0 += 32) {
        {
            const int r = tid >> 3;
            const int kq = (tid & 7) * 4;
#pragma unroll
            for (int rr = 0; rr < 2; ++rr) {
                const int row = row0 + r + rr * 32;
                float4 v = make_float4(0.f, 0.f, 0.f, 0.f);
                if (row < M) v = *reinterpret_cast<const float4*>(&X[row * K + k0 + kq]);
                if (RELU_IN) {
                    v.x = fmaxf(v.x, 0.f); v.y = fmaxf(v.y, 0.f);
                    v.z = fmaxf(v.z, 0.f); v.w = fmaxf(v.w, 0.f);
                }
                *reinterpret_cast<float4*>(&Xs[r + rr * 32][kq]) = v;
            }
        }
        {
            const int kr = tid >> 3;
#pragma unroll
            for (int i = 0; i < 4; ++i) {
                const int c4 = (tid & 7) + 8 * i;
                *reinterpret_cast<float4*>(&Ws[kr][c4 * 4]) =
                    *reinterpret_cast<const float4*>(&W[(k0 + kr) * 128 + c4 * 4]);
            }
        }
        __syncthreads();
#pragma unroll
        for (int kk = 0; kk < 32; ++kk) {
            float b[4];
            *reinterpret_cast<float4*>(b) = *reinterpret_cast<float4*>(&Ws[kk][tn * 4]);
#pragma unroll
            for (int m = 0; m < 8; ++m) {
                const float a = Xs[tm * 8 + m][kk];
                acc[m][0] = fmaf(a, b[0], acc[m][0]);
                acc[m][1] = fmaf(a, b[1], acc[m][1]);
                acc[m][2] = fmaf(a, b[2], acc[m][2]);
                acc[m][3] = fmaf(a, b[3], acc[m][3]);
            }
        }
        __syncthreads();
    }
#pragma unroll
    for (int m = 0; m < 8; ++m) {
        const int row = row0 + tm * 8 + m;
        if (row < M) {
            float4 v = make_float4(acc[m][0], acc[m][1], acc[m][2], acc[m][3]);
            *reinterpret_cast<float4*>(&H[row * 128 + tn * 4]) = v;
        }
    }
}

// ---------------------------------------------------------------- gather (fused init + aggregate)
__global__ __launch_bounds__(256) void gather_kernel(const int* __restrict__ rowptr,
                                                     const int* __restrict__ csr,
                                                     const float* __restrict__ H,
                                                     const float* __restrict__ dis,
                                                     const float* __restrict__ b,
                                                     float* __restrict__ AGG, int n) {
    int t = blockIdx.x * 256 + threadIdx.x;
    int node = t >> 5;
    if (node >= n) return;
    int lane = t & 31;
    const int beg = rowptr[node];
    const int end = rowptr[node + 1];
    const float d = dis[node];

    float4 acc;
    {
        float4 h = *reinterpret_cast<const float4*>(&H[node * 128 + lane * 4]);
        float4 bb = *reinterpret_cast<const float4*>(&b[lane * 4]);
        const float dd = d * d;
        acc.x = fmaf(h.x, dd, bb.x);
        acc.y = fmaf(h.y, dd, bb.y);
        acc.z = fmaf(h.z, dd, bb.z);
        acc.w = fmaf(h.w, dd, bb.w);
    }
    int i = beg;
    for (; i + 2 <= end; i += 2) {
        const int s0 = csr[i];
        const int s1 = csr[i + 1];
        const float e0 = dis[s0] * d;
        const float e1 = dis[s1] * d;
        float4 v0 = *reinterpret_cast<const float4*>(&H[s0 * 128 + lane * 4]);
        float4 v1 = *reinterpret_cast<const float4*>(&H[s1 * 128 + lane * 4]);
        acc.x = fmaf(v0.x, e0, acc.x);
        acc.y = fmaf(v0.y, e0, acc.y);
        acc.z = fmaf(v0.z, e0, acc.z);
        acc.w = fmaf(v0.w, e0, acc.w);
        acc.x = fmaf(v1.x, e1, acc.x);
        acc.y = fmaf(v1.y, e1, acc.y);
        acc.z = fmaf(v1.z, e1, acc.z);
        acc.w = fmaf(v1.w, e1, acc.w);
    }
    if (i < end) {
        const int s0 = csr[i];
        const float e0 = dis[s0] * d;
        float4 v0 = *reinterpret_cast<const float4*>(&H[s0 * 128 + lane * 4]);
        acc.x = fmaf(v0.x, e0, acc.x);
        acc.y = fmaf(v0.y, e0, acc.y);
        acc.z = fmaf(v0.z, e0, acc.z);
        acc.w = fmaf(v0.w, e0, acc.w);
    }
    *reinterpret_cast<float4*>(&AGG[node * 128 + lane * 4]) = acc;
}

// ---------------------------------------------------------------- pool (mean of relu(AGG) per graph)
__global__ __launch_bounds__(256) void pool_kernel(const float* __restrict__ AGG,
                                                   const int* __restrict__ batch,
                                                   float* __restrict__ pooled, int n) {
    const int g = blockIdx.x;
    int lo = 0, hi = n;
    while (lo < hi) { int mid = (lo + hi) >> 1; if (batch[mid] < g) lo = mid + 1; else hi = mid; }
    const int start = lo;
    hi = n;
    while (lo < hi) { int mid = (lo + hi) >> 1; if (batch[mid] < g + 1) lo = mid + 1; else hi = mid; }
    const int end = lo;

    const int f = threadIdx.x & 127;
    const int h = threadIdx.x >> 7;
    float s = 0.f;
    for (int i = start + h; i < end; i += 2) s += fmaxf(AGG[i * 128 + f], 0.f);
    __shared__ float sh[2][128];
    sh[h][f] = s;
    __syncthreads();
    if (h == 0) {
        float tot = sh[0][f] + sh[1][f];
        float cnt = (float)(end - start);
        pooled[g * 128 + f] = tot / fmaxf(cnt, 1.f);
    }
}

// ---------------------------------------------------------------- MLP head
__global__ __launch_bounds__(256) void mlp_kernel(const float* __restrict__ pooled,
                                                  const float* __restrict__ Wm1,
                                                  const float* __restrict__ bm1,
                                                  const float* __restrict__ Wm2,
                                                  const float* __restrict__ bm2,
                                                  float* __restrict__ out) {
    __shared__ float P[N_GRAPHS][HID];
    __shared__ float Wl[HID][MLP_HID];
    const int tid = threadIdx.x;
    for (int i = tid; i < N_GRAPHS * HID; i += 256) P[i >> 7][i & 127] = pooled[i];
    for (int i = tid; i < HID * MLP_HID; i += 256) Wl[i >> 6][i & 63] = Wm1[i];
    __syncthreads();
    const int g = tid >> 2;
    const int jb = tid & 3;
    float part = 0.f;
#pragma unroll
    for (int jj = 0; jj < 16; ++jj) {
        const int j = jb * 16 + jj;
        float z = bm1[j];
        for (int k = 0; k < HID; ++k) z = fmaf(P[g][k], Wl[k][j], z);
        z = fmaxf(z, 0.f);
        part = fmaf(z, Wm2[j], part);
    }
    part += __shfl_xor(part, 1);
    part += __shfl_xor(part, 2);
    if (jb == 0) out[g] = part + bm2[0];
}

extern "C" void kernel_launch(void* const* d_in, const int* in_sizes, int n_in,
                              void* d_out, int out_size, void* d_ws, size_t ws_size,
                              hipStream_t stream) {
    const float* x   = (const float*)d_in[0];
    const int*   ei  = (const int*)d_in[1];
    const int*   bat = (const int*)d_in[2];
    const float* W1  = (const float*)d_in[3];
    const float* b1  = (const float*)d_in[4];
    const float* W2  = (const float*)d_in[5];
    const float* b2  = (const float*)d_in[6];
    const float* W3  = (const float*)d_in[7];
    const float* b3  = (const float*)d_in[8];
    const float* Wm1 = (const float*)d_in[9];
    const float* bm1 = (const float*)d_in[10];
    const float* Wm2 = (const float*)d_in[11];
    const float* bm2 = (const float*)d_in[12];
    float* out = (float*)d_out;

    int*   cnt    = (int*)d_ws;                 // 50000
    int*   cursor = cnt + 50048;                // 50000
    int*   rowptr = cursor + 50048;             // 50001
    int*   csr    = rowptr + 50056;             // 800000
    int*   bsum   = csr + 800000;               // 256
    int*   boff   = bsum + 256;                 // 256
    float* dis    = (float*)(boff + 256);       // 50000
    float* H      = dis + 50048;                // 6.4M
    float* AGG    = H + N_NODES * HID;          // 6.4M
    float* pooled = AGG + N_NODES * HID;        // 8192

    hipMemsetAsync(cnt, 0, N_NODES * sizeof(int), stream);

    count_kernel<<<(N_EDGES + 255) / 256, 256, 0, stream>>>(ei + N_EDGES, cnt, N_EDGES);
    bsum_kernel<<<SCAN_BLOCKS, 256, 0, stream>>>(cnt, bsum);
    bscan_kernel<<<1, 256, 0, stream>>>(bsum, boff, rowptr);
    final_scan_kernel<<<SCAN_BLOCKS, 256, 0, stream>>>(cnt, boff, rowptr, cursor, dis);
    fill_kernel<<<(N_EDGES + 255) / 256, 256, 0, stream>>>(ei, cursor, csr, N_EDGES);

    const int gemm_blocks = (N_NODES + 63) / 64;
    const int gat_blocks  = (N_NODES * 32 + 255) / 256;

    // layer 1
    gemm_kernel<IN_DIM, false><<<gemm_blocks, 256, 0, stream>>>(x, W1, H, N_NODES);
    gather_kernel<<<gat_blocks, 256, 0, stream>>>(rowptr, csr, H, dis, b1, AGG, N_NODES);
    // layer 2
    gemm_kernel<HID, true><<<gemm_blocks, 256, 0, stream>>>(AGG, W2, H, N_NODES);
    gather_kernel<<<gat_blocks, 256, 0, stream>>>(rowptr, csr, H, dis, b2, AGG, N_NODES);
    // layer 3
    gemm_kernel<HID, true><<<gemm_blocks, 256, 0, stream>>>(AGG, W3, H, N_NODES);
    gather_kernel<<<gat_blocks, 256, 0, stream>>>(rowptr, csr, H, dis, b3, AGG, N_NODES);

    pool_kernel<<<N_GRAPHS, 256, 0, stream>>>(AGG, bat, pooled, N_NODES);
    mlp_kernel<<<1, 256, 0, stream>>>(pooled, Wm1, bm1, Wm2, bm2, out);
}

// Round 4
// 603.461 us; speedup vs baseline: 7.4120x; 1.1342x over previous
//
#include <hip/hip_runtime.h>
#include <hip/hip_bf16.h>

#define N_NODES 50000
#define N_EDGES 800000
#define N_GRAPHS 64
#define IN_DIM 384
#define HID 128
#define MLP_HID 64

#define SCAN_BLOCKS ((N_NODES + 255) / 256)   // 196
#define POOL_CHUNK 128
#define POOL_BLOCKS ((N_NODES + POOL_CHUNK - 1) / POOL_CHUNK)   // 391

// ---------------------------------------------------------------- degree count (int)
__global__ __launch_bounds__(256) void count_kernel(const int* __restrict__ dst,
                                                    int* __restrict__ cnt, int E) {
    int t = blockIdx.x * 256 + threadIdx.x;
    if (t < E) atomicAdd(&cnt[dst[t]], 1);
}

// ---------------------------------------------------------------- scan pass 1: block sums
__global__ __launch_bounds__(256) void bsum_kernel(const int* __restrict__ cnt,
                                                   int* __restrict__ bsum) {
    __shared__ int sh[256];
    const int t = threadIdx.x;
    const int i = blockIdx.x * 256 + t;
    sh[t] = (i < N_NODES) ? cnt[i] : 0;
    __syncthreads();
#pragma unroll
    for (int off = 128; off > 0; off >>= 1) {
        if (t < off) sh[t] += sh[t + off];
        __syncthreads();
    }
    if (t == 0) bsum[blockIdx.x] = sh[0];
}

// ---------------------------------------------------------------- scan pass 2: scan block sums
__global__ __launch_bounds__(256) void bscan_kernel(const int* __restrict__ bsum,
                                                    int* __restrict__ boff,
                                                    int* __restrict__ rowptr) {
    __shared__ int sh[256];
    const int t = threadIdx.x;
    int v = (t < SCAN_BLOCKS) ? bsum[t] : 0;
    sh[t] = v;
    __syncthreads();
#pragma unroll
    for (int off = 1; off < 256; off <<= 1) {
        int u = 0;
        if (t >= off) u = sh[t - off];
        __syncthreads();
        if (t >= off) sh[t] += u;
        __syncthreads();
    }
    if (t < SCAN_BLOCKS) boff[t] = sh[t] - v;   // exclusive
    if (t == 255) rowptr[N_NODES] = sh[255];    // total
}

// ---------------------------------------------------------------- scan pass 3: final
__global__ __launch_bounds__(256) void final_scan_kernel(const int* __restrict__ cnt,
                                                         const int* __restrict__ boff,
                                                         int* __restrict__ rowptr,
                                                         int* __restrict__ cursor,
                                                         float* __restrict__ dis) {
    __shared__ int sh[256];
    const int t = threadIdx.x;
    const int i = blockIdx.x * 256 + t;
    const int c = (i < N_NODES) ? cnt[i] : 0;
    sh[t] = c;
    __syncthreads();
#pragma unroll
    for (int off = 1; off < 256; off <<= 1) {
        int u = 0;
        if (t >= off) u = sh[t - off];
        __syncthreads();
        if (t >= off) sh[t] += u;
        __syncthreads();
    }
    if (i < N_NODES) {
        const int pos = boff[blockIdx.x] + sh[t] - c;   // exclusive prefix
        rowptr[i] = pos;
        cursor[i] = pos;
        dis[i] = rsqrtf((float)c + 1.0f);
    }
}

// ---------------------------------------------------------------- CSR fill
__global__ __launch_bounds__(256) void fill_kernel(const int* __restrict__ ei,
                                                   int* __restrict__ cursor,
                                                   int* __restrict__ csr, int E) {
    int e = blockIdx.x * 256 + threadIdx.x;
    if (e >= E) return;
    int s = ei[e];
    int d = ei[E + e];
    int pos = atomicAdd(&cursor[d], 1);
    csr[pos] = s;
}

// ---------------------------------------------------------------- GEMM  H = (relu?)X @ W
template <int K, bool RELU_IN>
__global__ __launch_bounds__(256) void gemm_kernel(const float* __restrict__ X,
                                                   const float* __restrict__ W,
                                                   float* __restrict__ H, int M) {
    __shared__ float Xs[64][32];
    __shared__ float Ws[32][128];
    const int tid = threadIdx.x;
    const int row0 = blockIdx.x * 64;
    const int tn = tid & 31;
    const int tm = tid >> 5;
    float acc[8][4] = {};

    for (int k0 = 0; k0 < K; k0 += 32) {
        {
            const int r = tid >> 3;
            const int kq = (tid & 7) * 4;
#pragma unroll
            for (int rr = 0; rr < 2; ++rr) {
                const int row = row0 + r + rr * 32;
                float4 v = make_float4(0.f, 0.f, 0.f, 0.f);
                if (row < M) v = *reinterpret_cast<const float4*>(&X[row * K + k0 + kq]);
                if (RELU_IN) {
                    v.x = fmaxf(v.x, 0.f); v.y = fmaxf(v.y, 0.f);
                    v.z = fmaxf(v.z, 0.f); v.w = fmaxf(v.w, 0.f);
                }
                *reinterpret_cast<float4*>(&Xs[r + rr * 32][kq]) = v;
            }
        }
        {
            const int kr = tid >> 3;
#pragma unroll
            for (int i = 0; i < 4; ++i) {
                const int c4 = (tid & 7) + 8 * i;
                *reinterpret_cast<float4*>(&Ws[kr][c4 * 4]) =
                    *reinterpret_cast<const float4*>(&W[(k0 + kr) * 128 + c4 * 4]);
            }
        }
        __syncthreads();
#pragma unroll
        for (int kk = 0; kk < 32; ++kk) {
            float b[4];
            *reinterpret_cast<float4*>(b) = *reinterpret_cast<float4*>(&Ws[kk][tn * 4]);
#pragma unroll
            for (int m = 0; m < 8; ++m) {
                const float a = Xs[tm * 8 + m][kk];
                acc[m][0] = fmaf(a, b[0], acc[m][0]);
                acc[m][1] = fmaf(a, b[1], acc[m][1]);
                acc[m][2] = fmaf(a, b[2], acc[m][2]);
                acc[m][3] = fmaf(a, b[3], acc[m][3]);
            }
        }
        __syncthreads();
    }
#pragma unroll
    for (int m = 0; m < 8; ++m) {
        const int row = row0 + tm * 8 + m;
        if (row < M) {
            float4 v = make_float4(acc[m][0], acc[m][1], acc[m][2], acc[m][3]);
            *reinterpret_cast<float4*>(&H[row * 128 + tn * 4]) = v;
        }
    }
}

// ---------------------------------------------------------------- gather (fused init + aggregate)
__global__ __launch_bounds__(256) void gather_kernel(const int* __restrict__ rowptr,
                                                     const int* __restrict__ csr,
                                                     const float* __restrict__ H,
                                                     const float* __restrict__ dis,
                                                     const float* __restrict__ b,
                                                     float* __restrict__ AGG, int n) {
    int t = blockIdx.x * 256 + threadIdx.x;
    int node = t >> 5;
    if (node >= n) return;
    int lane = t & 31;
    const int beg = rowptr[node];
    const int end = rowptr[node + 1];
    const float d = dis[node];

    float4 acc;
    {
        float4 h = *reinterpret_cast<const float4*>(&H[node * 128 + lane * 4]);
        float4 bb = *reinterpret_cast<const float4*>(&b[lane * 4]);
        const float dd = d * d;
        acc.x = fmaf(h.x, dd, bb.x);
        acc.y = fmaf(h.y, dd, bb.y);
        acc.z = fmaf(h.z, dd, bb.z);
        acc.w = fmaf(h.w, dd, bb.w);
    }
    int i = beg;
    for (; i + 2 <= end; i += 2) {
        const int s0 = csr[i];
        const int s1 = csr[i + 1];
        const float e0 = dis[s0] * d;
        const float e1 = dis[s1] * d;
        float4 v0 = *reinterpret_cast<const float4*>(&H[s0 * 128 + lane * 4]);
        float4 v1 = *reinterpret_cast<const float4*>(&H[s1 * 128 + lane * 4]);
        acc.x = fmaf(v0.x, e0, acc.x);
        acc.y = fmaf(v0.y, e0, acc.y);
        acc.z = fmaf(v0.z, e0, acc.z);
        acc.w = fmaf(v0.w, e0, acc.w);
        acc.x = fmaf(v1.x, e1, acc.x);
        acc.y = fmaf(v1.y, e1, acc.y);
        acc.z = fmaf(v1.z, e1, acc.z);
        acc.w = fmaf(v1.w, e1, acc.w);
    }
    if (i < end) {
        const int s0 = csr[i];
        const float e0 = dis[s0] * d;
        float4 v0 = *reinterpret_cast<const float4*>(&H[s0 * 128 + lane * 4]);
        acc.x = fmaf(v0.x, e0, acc.x);
        acc.y = fmaf(v0.y, e0, acc.y);
        acc.z = fmaf(v0.z, e0, acc.z);
        acc.w = fmaf(v0.w, e0, acc.w);
    }
    *reinterpret_cast<float4*>(&AGG[node * 128 + lane * 4]) = acc;
}

// ---------------------------------------------------------------- pool stage 1: chunked partial sums
// batch is sorted; each block owns POOL_CHUNK contiguous nodes, register-accumulates
// per-graph partials, flushes on graph change (rare) via atomicAdd.
__global__ __launch_bounds__(256) void pool1_kernel(const float* __restrict__ AGG,
                                                    const int* __restrict__ batch,
                                                    float* __restrict__ pooled, int n) {
    const int start = blockIdx.x * POOL_CHUNK;
    const int end = min(start + POOL_CHUNK, n);
    const int f = threadIdx.x & 127;
    const int h = threadIdx.x >> 7;
    int gcur = -1;
    float acc = 0.f;
    for (int i = start + h; i < end; i += 2) {
        const int g = batch[i];
        if (g != gcur) {
            if (gcur >= 0) atomicAdd(&pooled[gcur * HID + f], acc);
            gcur = g;
            acc = 0.f;
        }
        acc += fmaxf(AGG[i * HID + f], 0.f);
    }
    if (gcur >= 0) atomicAdd(&pooled[gcur * HID + f], acc);
}

// ---------------------------------------------------------------- pool stage 2: divide by counts
__global__ __launch_bounds__(128) void pooldiv_kernel(const int* __restrict__ batch,
                                                      float* __restrict__ pooled, int n) {
    const int g = blockIdx.x;
    int lo = 0, hi = n;
    while (lo < hi) { int mid = (lo + hi) >> 1; if (batch[mid] < g) lo = mid + 1; else hi = mid; }
    const int start = lo;
    hi = n;
    while (lo < hi) { int mid = (lo + hi) >> 1; if (batch[mid] < g + 1) lo = mid + 1; else hi = mid; }
    const float cnt = (float)(lo - start);
    pooled[g * HID + threadIdx.x] /= fmaxf(cnt, 1.f);
}

// ---------------------------------------------------------------- MLP head
__global__ __launch_bounds__(256) void mlp_kernel(const float* __restrict__ pooled,
                                                  const float* __restrict__ Wm1,
                                                  const float* __restrict__ bm1,
                                                  const float* __restrict__ Wm2,
                                                  const float* __restrict__ bm2,
                                                  float* __restrict__ out) {
    __shared__ float P[N_GRAPHS][HID];
    __shared__ float Wl[HID][MLP_HID];
    const int tid = threadIdx.x;
    for (int i = tid; i < N_GRAPHS * HID; i += 256) P[i >> 7][i & 127] = pooled[i];
    for (int i = tid; i < HID * MLP_HID; i += 256) Wl[i >> 6][i & 63] = Wm1[i];
    __syncthreads();
    const int g = tid >> 2;
    const int jb = tid & 3;
    float part = 0.f;
#pragma unroll
    for (int jj = 0; jj < 16; ++jj) {
        const int j = jb * 16 + jj;
        float z = bm1[j];
        for (int k = 0; k < HID; ++k) z = fmaf(P[g][k], Wl[k][j], z);
        z = fmaxf(z, 0.f);
        part = fmaf(z, Wm2[j], part);
    }
    part += __shfl_xor(part, 1);
    part += __shfl_xor(part, 2);
    if (jb == 0) out[g] = part + bm2[0];
}

extern "C" void kernel_launch(void* const* d_in, const int* in_sizes, int n_in,
                              void* d_out, int out_size, void* d_ws, size_t ws_size,
                              hipStream_t stream) {
    const float* x   = (const float*)d_in[0];
    const int*   ei  = (const int*)d_in[1];
    const int*   bat = (const int*)d_in[2];
    const float* W1  = (const float*)d_in[3];
    const float* b1  = (const float*)d_in[4];
    const float* W2  = (const float*)d_in[5];
    const float* b2  = (const float*)d_in[6];
    const float* W3  = (const float*)d_in[7];
    const float* b3  = (const float*)d_in[8];
    const float* Wm1 = (const float*)d_in[9];
    const float* bm1 = (const float*)d_in[10];
    const float* Wm2 = (const float*)d_in[11];
    const float* bm2 = (const float*)d_in[12];
    float* out = (float*)d_out;

    int*   cnt    = (int*)d_ws;                 // 50000
    int*   cursor = cnt + 50048;                // 50000
    int*   rowptr = cursor + 50048;             // 50001
    int*   csr    = rowptr + 50056;             // 800000
    int*   bsum   = csr + 800000;               // 256
    int*   boff   = bsum + 256;                 // 256
    float* dis    = (float*)(boff + 256);       // 50000
    float* H      = dis + 50048;                // 6.4M
    float* AGG    = H + N_NODES * HID;          // 6.4M
    float* pooled = AGG + N_NODES * HID;        // 8192

    hipMemsetAsync(cnt, 0, N_NODES * sizeof(int), stream);
    hipMemsetAsync(pooled, 0, N_GRAPHS * HID * sizeof(float), stream);

    count_kernel<<<(N_EDGES + 255) / 256, 256, 0, stream>>>(ei + N_EDGES, cnt, N_EDGES);
    bsum_kernel<<<SCAN_BLOCKS, 256, 0, stream>>>(cnt, bsum);
    bscan_kernel<<<1, 256, 0, stream>>>(bsum, boff, rowptr);
    final_scan_kernel<<<SCAN_BLOCKS, 256, 0, stream>>>(cnt, boff, rowptr, cursor, dis);
    fill_kernel<<<(N_EDGES + 255) / 256, 256, 0, stream>>>(ei, cursor, csr, N_EDGES);

    const int gemm_blocks = (N_NODES + 63) / 64;
    const int gat_blocks  = (N_NODES * 32 + 255) / 256;

    // layer 1
    gemm_kernel<IN_DIM, false><<<gemm_blocks, 256, 0, stream>>>(x, W1, H, N_NODES);
    gather_kernel<<<gat_blocks, 256, 0, stream>>>(rowptr, csr, H, dis, b1, AGG, N_NODES);
    // layer 2
    gemm_kernel<HID, true><<<gemm_blocks, 256, 0, stream>>>(AGG, W2, H, N_NODES);
    gather_kernel<<<gat_blocks, 256, 0, stream>>>(rowptr, csr, H, dis, b2, AGG, N_NODES);
    // layer 3
    gemm_kernel<HID, true><<<gemm_blocks, 256, 0, stream>>>(AGG, W3, H, N_NODES);
    gather_kernel<<<gat_blocks, 256, 0, stream>>>(rowptr, csr, H, dis, b3, AGG, N_NODES);

    pool1_kernel<<<POOL_BLOCKS, 256, 0, stream>>>(AGG, bat, pooled, N_NODES);
    pooldiv_kernel<<<N_GRAPHS, 128, 0, stream>>>(bat, pooled, N_NODES);
    mlp_kernel<<<1, 256, 0, stream>>>(pooled, Wm1, bm1, Wm2, bm2, out);
}

// Round 5
// 537.702 us; speedup vs baseline: 8.3184x; 1.1223x over previous
//
#include <hip/hip_runtime.h>
#include <hip/hip_bf16.h>

#define N_NODES 50000
#define N_EDGES 800000
#define N_GRAPHS 64
#define IN_DIM 384
#define HID 128
#define MLP_HID 64

#define SCAN_BLOCKS ((N_NODES + 255) / 256)   // 196
#define POOL_CHUNK 128
#define POOL_BLOCKS ((N_NODES + POOL_CHUNK - 1) / POOL_CHUNK)   // 391
#define GEMM_BLOCKS ((N_NODES + 127) / 128)   // 391

typedef __attribute__((ext_vector_type(8))) short short8;
typedef __attribute__((ext_vector_type(4))) float f32x4;
typedef unsigned int u32;

// ---------------------------------------------------------------- degree count (int)
__global__ __launch_bounds__(256) void count_kernel(const int* __restrict__ dst,
                                                    int* __restrict__ cnt, int E) {
    int t = blockIdx.x * 256 + threadIdx.x;
    if (t < E) atomicAdd(&cnt[dst[t]], 1);
}

// ---------------------------------------------------------------- scan pass 1: block sums
__global__ __launch_bounds__(256) void bsum_kernel(const int* __restrict__ cnt,
                                                   int* __restrict__ bsum) {
    __shared__ int sh[256];
    const int t = threadIdx.x;
    const int i = blockIdx.x * 256 + t;
    sh[t] = (i < N_NODES) ? cnt[i] : 0;
    __syncthreads();
#pragma unroll
    for (int off = 128; off > 0; off >>= 1) {
        if (t < off) sh[t] += sh[t + off];
        __syncthreads();
    }
    if (t == 0) bsum[blockIdx.x] = sh[0];
}

// ---------------------------------------------------------------- scan pass 2: scan block sums
__global__ __launch_bounds__(256) void bscan_kernel(const int* __restrict__ bsum,
                                                    int* __restrict__ boff,
                                                    int* __restrict__ rowptr) {
    __shared__ int sh[256];
    const int t = threadIdx.x;
    int v = (t < SCAN_BLOCKS) ? bsum[t] : 0;
    sh[t] = v;
    __syncthreads();
#pragma unroll
    for (int off = 1; off < 256; off <<= 1) {
        int u = 0;
        if (t >= off) u = sh[t - off];
        __syncthreads();
        if (t >= off) sh[t] += u;
        __syncthreads();
    }
    if (t < SCAN_BLOCKS) boff[t] = sh[t] - v;   // exclusive
    if (t == 255) rowptr[N_NODES] = sh[255];    // total
}

// ---------------------------------------------------------------- scan pass 3: final
__global__ __launch_bounds__(256) void final_scan_kernel(const int* __restrict__ cnt,
                                                         const int* __restrict__ boff,
                                                         int* __restrict__ rowptr,
                                                         int* __restrict__ cursor,
                                                         float* __restrict__ dis) {
    __shared__ int sh[256];
    const int t = threadIdx.x;
    const int i = blockIdx.x * 256 + t;
    const int c = (i < N_NODES) ? cnt[i] : 0;
    sh[t] = c;
    __syncthreads();
#pragma unroll
    for (int off = 1; off < 256; off <<= 1) {
        int u = 0;
        if (t >= off) u = sh[t - off];
        __syncthreads();
        if (t >= off) sh[t] += u;
        __syncthreads();
    }
    if (i < N_NODES) {
        const int pos = boff[blockIdx.x] + sh[t] - c;   // exclusive prefix
        rowptr[i] = pos;
        cursor[i] = pos;
        dis[i] = rsqrtf((float)c + 1.0f);
    }
}

// ---------------------------------------------------------------- CSR fill
__global__ __launch_bounds__(256) void fill_kernel(const int* __restrict__ ei,
                                                   int* __restrict__ cursor,
                                                   int* __restrict__ csr, int E) {
    int e = blockIdx.x * 256 + threadIdx.x;
    if (e >= E) return;
    int s = ei[e];
    int d = ei[E + e];
    int pos = atomicAdd(&cursor[d], 1);
    csr[pos] = s;
}

// ---------------------------------------------------------------- W split: fp32 [K][128] ->
// truncation-split bf16 hi/lo, TRANSPOSED to [128][K] for contiguous-k staging.
__global__ __launch_bounds__(256) void wsplit_kernel(const float* __restrict__ W,
                                                     ushort* __restrict__ hi,
                                                     ushort* __restrict__ lo, int K) {
    int t = blockIdx.x * 256 + threadIdx.x;
    if (t >= K * 128) return;
    const int k = t >> 7;
    const int c = t & 127;
    const float f = W[t];
    const u32 u = __float_as_uint(f);
    const u32 h = u & 0xFFFF0000u;
    const float lf = f - __uint_as_float(h);
    hi[c * K + k] = (ushort)(u >> 16);
    lo[c * K + k] = (ushort)(__float_as_uint(lf) >> 16);
}

// ---------------------------------------------------------------- MFMA split-bf16 GEMM
// H[M,128] = (relu?)X[M,K] @ W[K,128], W pre-split+transposed (Wthi/Wtlo: [128][K] bf16).
// 3-term split: Ahi*Bhi + Ahi*Blo + Alo*Bhi, fp32 accum. err ~2^-16 rel.
// Block: 128 rows x 128 cols, 4 waves in 2x2, each wave 64x64 (4x4 16x16 frags).
template <int K, bool RELU_IN>
__global__ __launch_bounds__(256) void gemm_mfma_kernel(const float* __restrict__ X,
                                                        const ushort* __restrict__ Wthi,
                                                        const ushort* __restrict__ Wtlo,
                                                        float* __restrict__ H, int M) {
    __shared__ ushort Ahi[128][40];   // stride 40 shorts = 80B: 16B-aligned rows, ~2-way banks
    __shared__ ushort Alo[128][40];
    __shared__ ushort Bhi[128][40];
    __shared__ ushort Blo[128][40];

    const int tid = threadIdx.x;
    const int row0 = blockIdx.x * 128;

    const int srow = tid >> 1;            // staging row/col 0..127
    const int skq  = (tid & 1) << 4;      // k-offset 0 or 16

    const int lane = tid & 63;
    const int wave = tid >> 6;
    const int wr = (wave >> 1) * 64;
    const int wc = (wave & 1) * 64;
    const int li = lane & 15;
    const int kb = (lane >> 4) << 3;      // k-block 0/8/16/24

    f32x4 acc[4][4];
#pragma unroll
    for (int m = 0; m < 4; ++m)
#pragma unroll
        for (int n = 0; n < 4; ++n) acc[m][n] = (f32x4){0.f, 0.f, 0.f, 0.f};

    for (int k0 = 0; k0 < K; k0 += 32) {
        // ---- stage A: load fp32, optional relu, truncation-split to hi/lo bf16
        {
            const int gr = row0 + srow;
            const float* src = &X[(size_t)(gr < M ? gr : (M - 1)) * K + k0 + skq];
            float f[16];
            *reinterpret_cast<float4*>(f)      = *reinterpret_cast<const float4*>(src);
            *reinterpret_cast<float4*>(f + 4)  = *reinterpret_cast<const float4*>(src + 4);
            *reinterpret_cast<float4*>(f + 8)  = *reinterpret_cast<const float4*>(src + 8);
            *reinterpret_cast<float4*>(f + 12) = *reinterpret_cast<const float4*>(src + 12);
            u32 hp[8], lp[8];
#pragma unroll
            for (int i = 0; i < 8; ++i) {
                float f0 = f[2 * i], f1 = f[2 * i + 1];
                if (RELU_IN) { f0 = fmaxf(f0, 0.f); f1 = fmaxf(f1, 0.f); }
                const u32 u0 = __float_as_uint(f0), u1 = __float_as_uint(f1);
                const u32 h0 = u0 & 0xFFFF0000u, h1 = u1 & 0xFFFF0000u;
                const float l0 = f0 - __uint_as_float(h0);
                const float l1 = f1 - __uint_as_float(h1);
                hp[i] = (h0 >> 16) | h1;
                lp[i] = (__float_as_uint(l0) >> 16) | (__float_as_uint(l1) & 0xFFFF0000u);
            }
            u32* dh = (u32*)&Ahi[srow][skq];
            u32* dl = (u32*)&Alo[srow][skq];
            *reinterpret_cast<uint4*>(dh)     = make_uint4(hp[0], hp[1], hp[2], hp[3]);
            *reinterpret_cast<uint4*>(dh + 4) = make_uint4(hp[4], hp[5], hp[6], hp[7]);
            *reinterpret_cast<uint4*>(dl)     = make_uint4(lp[0], lp[1], lp[2], lp[3]);
            *reinterpret_cast<uint4*>(dl + 4) = make_uint4(lp[4], lp[5], lp[6], lp[7]);
        }
        // ---- stage B: straight bf16 copy from pre-split transposed W
        {
            const ushort* sh = &Wthi[srow * K + k0 + skq];
            const ushort* sl = &Wtlo[srow * K + k0 + skq];
            *reinterpret_cast<uint4*>(&Bhi[srow][skq])     = *reinterpret_cast<const uint4*>(sh);
            *reinterpret_cast<uint4*>(&Bhi[srow][skq + 8]) = *reinterpret_cast<const uint4*>(sh + 8);
            *reinterpret_cast<uint4*>(&Blo[srow][skq])     = *reinterpret_cast<const uint4*>(sl);
            *reinterpret_cast<uint4*>(&Blo[srow][skq + 8]) = *reinterpret_cast<const uint4*>(sl + 8);
        }
        __syncthreads();
        // ---- compute
        short8 ah[4], al[4];
#pragma unroll
        for (int m = 0; m < 4; ++m) {
            ah[m] = *reinterpret_cast<const short8*>(&Ahi[wr + m * 16 + li][kb]);
            al[m] = *reinterpret_cast<const short8*>(&Alo[wr + m * 16 + li][kb]);
        }
#pragma unroll
        for (int n = 0; n < 4; ++n) {
            const short8 bh = *reinterpret_cast<const short8*>(&Bhi[wc + n * 16 + li][kb]);
            const short8 bl = *reinterpret_cast<const short8*>(&Blo[wc + n * 16 + li][kb]);
#pragma unroll
            for (int m = 0; m < 4; ++m) {
                acc[m][n] = __builtin_amdgcn_mfma_f32_16x16x32_bf16(ah[m], bh, acc[m][n], 0, 0, 0);
                acc[m][n] = __builtin_amdgcn_mfma_f32_16x16x32_bf16(ah[m], bl, acc[m][n], 0, 0, 0);
                acc[m][n] = __builtin_amdgcn_mfma_f32_16x16x32_bf16(al[m], bh, acc[m][n], 0, 0, 0);
            }
        }
        __syncthreads();
    }
    // ---- store: D frag: col = lane&15, row = (lane>>4)*4 + r
    const int rbase = (lane >> 4) << 2;
#pragma unroll
    for (int m = 0; m < 4; ++m) {
        const int gr0 = row0 + wr + m * 16 + rbase;
#pragma unroll
        for (int r = 0; r < 4; ++r) {
            const int grow = gr0 + r;
            if (grow < M) {
#pragma unroll
                for (int n = 0; n < 4; ++n) {
                    H[(size_t)grow * 128 + wc + n * 16 + li] = acc[m][n][r];
                }
            }
        }
    }
}

// ---------------------------------------------------------------- gather (fused init + aggregate)
__global__ __launch_bounds__(256) void gather_kernel(const int* __restrict__ rowptr,
                                                     const int* __restrict__ csr,
                                                     const float* __restrict__ H,
                                                     const float* __restrict__ dis,
                                                     const float* __restrict__ b,
                                                     float* __restrict__ AGG, int n) {
    int t = blockIdx.x * 256 + threadIdx.x;
    int node = t >> 5;
    if (node >= n) return;
    int lane = t & 31;
    const int beg = rowptr[node];
    const int end = rowptr[node + 1];
    const float d = dis[node];

    float4 acc;
    {
        float4 h = *reinterpret_cast<const float4*>(&H[node * 128 + lane * 4]);
        float4 bb = *reinterpret_cast<const float4*>(&b[lane * 4]);
        const float dd = d * d;
        acc.x = fmaf(h.x, dd, bb.x);
        acc.y = fmaf(h.y, dd, bb.y);
        acc.z = fmaf(h.z, dd, bb.z);
        acc.w = fmaf(h.w, dd, bb.w);
    }
    int i = beg;
    for (; i + 2 <= end; i += 2) {
        const int s0 = csr[i];
        const int s1 = csr[i + 1];
        const float e0 = dis[s0] * d;
        const float e1 = dis[s1] * d;
        float4 v0 = *reinterpret_cast<const float4*>(&H[s0 * 128 + lane * 4]);
        float4 v1 = *reinterpret_cast<const float4*>(&H[s1 * 128 + lane * 4]);
        acc.x = fmaf(v0.x, e0, acc.x);
        acc.y = fmaf(v0.y, e0, acc.y);
        acc.z = fmaf(v0.z, e0, acc.z);
        acc.w = fmaf(v0.w, e0, acc.w);
        acc.x = fmaf(v1.x, e1, acc.x);
        acc.y = fmaf(v1.y, e1, acc.y);
        acc.z = fmaf(v1.z, e1, acc.z);
        acc.w = fmaf(v1.w, e1, acc.w);
    }
    if (i < end) {
        const int s0 = csr[i];
        const float e0 = dis[s0] * d;
        float4 v0 = *reinterpret_cast<const float4*>(&H[s0 * 128 + lane * 4]);
        acc.x = fmaf(v0.x, e0, acc.x);
        acc.y = fmaf(v0.y, e0, acc.y);
        acc.z = fmaf(v0.z, e0, acc.z);
        acc.w = fmaf(v0.w, e0, acc.w);
    }
    *reinterpret_cast<float4*>(&AGG[node * 128 + lane * 4]) = acc;
}

// ---------------------------------------------------------------- pool stage 1
__global__ __launch_bounds__(256) void pool1_kernel(const float* __restrict__ AGG,
                                                    const int* __restrict__ batch,
                                                    float* __restrict__ pooled, int n) {
    const int start = blockIdx.x * POOL_CHUNK;
    const int end = min(start + POOL_CHUNK, n);
    const int f = threadIdx.x & 127;
    const int h = threadIdx.x >> 7;
    int gcur = -1;
    float acc = 0.f;
    for (int i = start + h; i < end; i += 2) {
        const int g = batch[i];
        if (g != gcur) {
            if (gcur >= 0) atomicAdd(&pooled[gcur * HID + f], acc);
            gcur = g;
            acc = 0.f;
        }
        acc += fmaxf(AGG[i * HID + f], 0.f);
    }
    if (gcur >= 0) atomicAdd(&pooled[gcur * HID + f], acc);
}

// ---------------------------------------------------------------- pool stage 2
__global__ __launch_bounds__(128) void pooldiv_kernel(const int* __restrict__ batch,
                                                      float* __restrict__ pooled, int n) {
    const int g = blockIdx.x;
    int lo = 0, hi = n;
    while (lo < hi) { int mid = (lo + hi) >> 1; if (batch[mid] < g) lo = mid + 1; else hi = mid; }
    const int start = lo;
    hi = n;
    while (lo < hi) { int mid = (lo + hi) >> 1; if (batch[mid] < g + 1) lo = mid + 1; else hi = mid; }
    const float cnt = (float)(lo - start);
    pooled[g * HID + threadIdx.x] /= fmaxf(cnt, 1.f);
}

// ---------------------------------------------------------------- MLP head
__global__ __launch_bounds__(256) void mlp_kernel(const float* __restrict__ pooled,
                                                  const float* __restrict__ Wm1,
                                                  const float* __restrict__ bm1,
                                                  const float* __restrict__ Wm2,
                                                  const float* __restrict__ bm2,
                                                  float* __restrict__ out) {
    __shared__ float P[N_GRAPHS][HID];
    __shared__ float Wl[HID][MLP_HID];
    const int tid = threadIdx.x;
    for (int i = tid; i < N_GRAPHS * HID; i += 256) P[i >> 7][i & 127] = pooled[i];
    for (int i = tid; i < HID * MLP_HID; i += 256) Wl[i >> 6][i & 63] = Wm1[i];
    __syncthreads();
    const int g = tid >> 2;
    const int jb = tid & 3;
    float part = 0.f;
#pragma unroll
    for (int jj = 0; jj < 16; ++jj) {
        const int j = jb * 16 + jj;
        float z = bm1[j];
        for (int k = 0; k < HID; ++k) z = fmaf(P[g][k], Wl[k][j], z);
        z = fmaxf(z, 0.f);
        part = fmaf(z, Wm2[j], part);
    }
    part += __shfl_xor(part, 1);
    part += __shfl_xor(part, 2);
    if (jb == 0) out[g] = part + bm2[0];
}

extern "C" void kernel_launch(void* const* d_in, const int* in_sizes, int n_in,
                              void* d_out, int out_size, void* d_ws, size_t ws_size,
                              hipStream_t stream) {
    const float* x   = (const float*)d_in[0];
    const int*   ei  = (const int*)d_in[1];
    const int*   bat = (const int*)d_in[2];
    const float* W1  = (const float*)d_in[3];
    const float* b1  = (const float*)d_in[4];
    const float* W2  = (const float*)d_in[5];
    const float* b2  = (const float*)d_in[6];
    const float* W3  = (const float*)d_in[7];
    const float* b3  = (const float*)d_in[8];
    const float* Wm1 = (const float*)d_in[9];
    const float* bm1 = (const float*)d_in[10];
    const float* Wm2 = (const float*)d_in[11];
    const float* bm2 = (const float*)d_in[12];
    float* out = (float*)d_out;

    int*   cnt    = (int*)d_ws;                 // 50000
    int*   cursor = cnt + 50048;                // 50000
    int*   rowptr = cursor + 50048;             // 50001
    int*   csr    = rowptr + 50056;             // 800000
    int*   bsum   = csr + 800000;               // 256
    int*   boff   = bsum + 256;                 // 256
    float* dis    = (float*)(boff + 256);       // 50000
    float* H      = dis + 50048;                // 6.4M
    float* AGG    = H + N_NODES * HID;          // 6.4M
    float* pooled = AGG + N_NODES * HID;        // 8192
    ushort* wt1hi = (ushort*)(pooled + 8192);   // 49152
    ushort* wt1lo = wt1hi + IN_DIM * HID;       // 49152
    ushort* wt2hi = wt1lo + IN_DIM * HID;       // 16384
    ushort* wt2lo = wt2hi + HID * HID;
    ushort* wt3hi = wt2lo + HID * HID;
    ushort* wt3lo = wt3hi + HID * HID;

    hipMemsetAsync(cnt, 0, N_NODES * sizeof(int), stream);
    hipMemsetAsync(pooled, 0, N_GRAPHS * HID * sizeof(float), stream);

    count_kernel<<<(N_EDGES + 255) / 256, 256, 0, stream>>>(ei + N_EDGES, cnt, N_EDGES);
    bsum_kernel<<<SCAN_BLOCKS, 256, 0, stream>>>(cnt, bsum);
    bscan_kernel<<<1, 256, 0, stream>>>(bsum, boff, rowptr);
    final_scan_kernel<<<SCAN_BLOCKS, 256, 0, stream>>>(cnt, boff, rowptr, cursor, dis);
    fill_kernel<<<(N_EDGES + 255) / 256, 256, 0, stream>>>(ei, cursor, csr, N_EDGES);

    wsplit_kernel<<<(IN_DIM * HID + 255) / 256, 256, 0, stream>>>(W1, wt1hi, wt1lo, IN_DIM);
    wsplit_kernel<<<(HID * HID + 255) / 256, 256, 0, stream>>>(W2, wt2hi, wt2lo, HID);
    wsplit_kernel<<<(HID * HID + 255) / 256, 256, 0, stream>>>(W3, wt3hi, wt3lo, HID);

    const int gat_blocks = (N_NODES * 32 + 255) / 256;

    // layer 1
    gemm_mfma_kernel<IN_DIM, false><<<GEMM_BLOCKS, 256, 0, stream>>>(x, wt1hi, wt1lo, H, N_NODES);
    gather_kernel<<<gat_blocks, 256, 0, stream>>>(rowptr, csr, H, dis, b1, AGG, N_NODES);
    // layer 2
    gemm_mfma_kernel<HID, true><<<GEMM_BLOCKS, 256, 0, stream>>>(AGG, wt2hi, wt2lo, H, N_NODES);
    gather_kernel<<<gat_blocks, 256, 0, stream>>>(rowptr, csr, H, dis, b2, AGG, N_NODES);
    // layer 3
    gemm_mfma_kernel<HID, true><<<GEMM_BLOCKS, 256, 0, stream>>>(AGG, W3 ? wt3hi : wt3hi, wt3lo, H, N_NODES);
    gather_kernel<<<gat_blocks, 256, 0, stream>>>(rowptr, csr, H, dis, b3, AGG, N_NODES);

    pool1_kernel<<<POOL_BLOCKS, 256, 0, stream>>>(AGG, bat, pooled, N_NODES);
    pooldiv_kernel<<<N_GRAPHS, 128, 0, stream>>>(bat, pooled, N_NODES);
    mlp_kernel<<<1, 256, 0, stream>>>(pooled, Wm1, bm1, Wm2, bm2, out);
}

// Round 6
// 522.843 us; speedup vs baseline: 8.5548x; 1.0284x over previous
//
#include <hip/hip_runtime.h>
#include <hip/hip_bf16.h>

#define N_NODES 50000
#define N_EDGES 800000
#define N_GRAPHS 64
#define IN_DIM 384
#define HID 128
#define MLP_HID 64

#define SCAN_BLOCKS ((N_NODES + 255) / 256)   // 196
#define GEMM_BLOCKS ((N_NODES + 127) / 128)   // 391
#define GATHER_BLOCKS (N_NODES / 4)           // 12500 (4 waves/block, 1 node/wave)

typedef __attribute__((ext_vector_type(8))) short short8;
typedef __attribute__((ext_vector_type(4))) float f32x4;
typedef unsigned int u32;

// ---------------------------------------------------------------- degree count (int)
__global__ __launch_bounds__(256) void count_kernel(const int* __restrict__ dst,
                                                    int* __restrict__ cnt, int E) {
    int t = blockIdx.x * 256 + threadIdx.x;
    if (t < E) atomicAdd(&cnt[dst[t]], 1);
}

// ---------------------------------------------------------------- scan pass 1: block sums
__global__ __launch_bounds__(256) void bsum_kernel(const int* __restrict__ cnt,
                                                   int* __restrict__ bsum) {
    __shared__ int sh[256];
    const int t = threadIdx.x;
    const int i = blockIdx.x * 256 + t;
    sh[t] = (i < N_NODES) ? cnt[i] : 0;
    __syncthreads();
#pragma unroll
    for (int off = 128; off > 0; off >>= 1) {
        if (t < off) sh[t] += sh[t + off];
        __syncthreads();
    }
    if (t == 0) bsum[blockIdx.x] = sh[0];
}

// ---------------------------------------------------------------- scan pass 2: scan block sums
__global__ __launch_bounds__(256) void bscan_kernel(const int* __restrict__ bsum,
                                                    int* __restrict__ boff,
                                                    int* __restrict__ rowptr) {
    __shared__ int sh[256];
    const int t = threadIdx.x;
    int v = (t < SCAN_BLOCKS) ? bsum[t] : 0;
    sh[t] = v;
    __syncthreads();
#pragma unroll
    for (int off = 1; off < 256; off <<= 1) {
        int u = 0;
        if (t >= off) u = sh[t - off];
        __syncthreads();
        if (t >= off) sh[t] += u;
        __syncthreads();
    }
    if (t < SCAN_BLOCKS) boff[t] = sh[t] - v;   // exclusive
    if (t == 255) rowptr[N_NODES] = sh[255];    // total
}

// ---------------------------------------------------------------- scan pass 3: final
__global__ __launch_bounds__(256) void final_scan_kernel(const int* __restrict__ cnt,
                                                         const int* __restrict__ boff,
                                                         int* __restrict__ rowptr,
                                                         int* __restrict__ cursor,
                                                         float* __restrict__ dis) {
    __shared__ int sh[256];
    const int t = threadIdx.x;
    const int i = blockIdx.x * 256 + t;
    const int c = (i < N_NODES) ? cnt[i] : 0;
    sh[t] = c;
    __syncthreads();
#pragma unroll
    for (int off = 1; off < 256; off <<= 1) {
        int u = 0;
        if (t >= off) u = sh[t - off];
        __syncthreads();
        if (t >= off) sh[t] += u;
        __syncthreads();
    }
    if (i < N_NODES) {
        const int pos = boff[blockIdx.x] + sh[t] - c;   // exclusive prefix
        rowptr[i] = pos;
        cursor[i] = pos;
        dis[i] = rsqrtf((float)c + 1.0f);
    }
}

// ---------------------------------------------------------------- CSR fill
__global__ __launch_bounds__(256) void fill_kernel(const int* __restrict__ ei,
                                                   int* __restrict__ cursor,
                                                   int* __restrict__ csr, int E) {
    int e = blockIdx.x * 256 + threadIdx.x;
    if (e >= E) return;
    int s = ei[e];
    int d = ei[E + e];
    int pos = atomicAdd(&cursor[d], 1);
    csr[pos] = s;
}

// ---------------------------------------------------------------- W split (all 3 weights, one dispatch)
// fp32 [K][128] -> truncation-split bf16 hi/lo, transposed to [128][K].
__device__ __forceinline__ void wsplit_one(const float* W, ushort* hi, ushort* lo,
                                           int K, int t) {
    const int k = t >> 7;
    const int c = t & 127;
    const float f = W[t];
    const u32 u = __float_as_uint(f);
    const u32 h = u & 0xFFFF0000u;
    const float lf = f - __uint_as_float(h);
    hi[c * K + k] = (ushort)(u >> 16);
    lo[c * K + k] = (ushort)(__float_as_uint(lf) >> 16);
}

__global__ __launch_bounds__(256) void wsplit_kernel(const float* __restrict__ W1,
                                                     const float* __restrict__ W2,
                                                     const float* __restrict__ W3,
                                                     ushort* __restrict__ w1hi, ushort* __restrict__ w1lo,
                                                     ushort* __restrict__ w2hi, ushort* __restrict__ w2lo,
                                                     ushort* __restrict__ w3hi, ushort* __restrict__ w3lo) {
    int t = blockIdx.x * 256 + threadIdx.x;
    if (t < IN_DIM * HID) wsplit_one(W1, w1hi, w1lo, IN_DIM, t);
    if (t < HID * HID) {
        wsplit_one(W2, w2hi, w2lo, HID, t);
        wsplit_one(W3, w3hi, w3lo, HID, t);
    }
}

// ---------------------------------------------------------------- MFMA split-bf16 GEMM
// Hs[M,128] = ((relu?)X[M,K] @ W[K,128]) * dis[row]  (dis pre-scaling fused in epilogue)
template <int K, bool RELU_IN>
__global__ __launch_bounds__(256) void gemm_mfma_kernel(const float* __restrict__ X,
                                                        const ushort* __restrict__ Wthi,
                                                        const ushort* __restrict__ Wtlo,
                                                        const float* __restrict__ dis,
                                                        float* __restrict__ Hs, int M) {
    __shared__ ushort Ahi[128][40];
    __shared__ ushort Alo[128][40];
    __shared__ ushort Bhi[128][40];
    __shared__ ushort Blo[128][40];

    const int tid = threadIdx.x;
    const int row0 = blockIdx.x * 128;

    const int srow = tid >> 1;
    const int skq  = (tid & 1) << 4;

    const int lane = tid & 63;
    const int wave = tid >> 6;
    const int wr = (wave >> 1) * 64;
    const int wc = (wave & 1) * 64;
    const int li = lane & 15;
    const int kb = (lane >> 4) << 3;

    f32x4 acc[4][4];
#pragma unroll
    for (int m = 0; m < 4; ++m)
#pragma unroll
        for (int n = 0; n < 4; ++n) acc[m][n] = (f32x4){0.f, 0.f, 0.f, 0.f};

    for (int k0 = 0; k0 < K; k0 += 32) {
        {
            const int gr = row0 + srow;
            const float* src = &X[(size_t)(gr < M ? gr : (M - 1)) * K + k0 + skq];
            float f[16];
            *reinterpret_cast<float4*>(f)      = *reinterpret_cast<const float4*>(src);
            *reinterpret_cast<float4*>(f + 4)  = *reinterpret_cast<const float4*>(src + 4);
            *reinterpret_cast<float4*>(f + 8)  = *reinterpret_cast<const float4*>(src + 8);
            *reinterpret_cast<float4*>(f + 12) = *reinterpret_cast<const float4*>(src + 12);
            u32 hp[8], lp[8];
#pragma unroll
            for (int i = 0; i < 8; ++i) {
                float f0 = f[2 * i], f1 = f[2 * i + 1];
                if (RELU_IN) { f0 = fmaxf(f0, 0.f); f1 = fmaxf(f1, 0.f); }
                const u32 u0 = __float_as_uint(f0), u1 = __float_as_uint(f1);
                const u32 h0 = u0 & 0xFFFF0000u, h1 = u1 & 0xFFFF0000u;
                const float l0 = f0 - __uint_as_float(h0);
                const float l1 = f1 - __uint_as_float(h1);
                hp[i] = (h0 >> 16) | h1;
                lp[i] = (__float_as_uint(l0) >> 16) | (__float_as_uint(l1) & 0xFFFF0000u);
            }
            u32* dh = (u32*)&Ahi[srow][skq];
            u32* dl = (u32*)&Alo[srow][skq];
            *reinterpret_cast<uint4*>(dh)     = make_uint4(hp[0], hp[1], hp[2], hp[3]);
            *reinterpret_cast<uint4*>(dh + 4) = make_uint4(hp[4], hp[5], hp[6], hp[7]);
            *reinterpret_cast<uint4*>(dl)     = make_uint4(lp[0], lp[1], lp[2], lp[3]);
            *reinterpret_cast<uint4*>(dl + 4) = make_uint4(lp[4], lp[5], lp[6], lp[7]);
        }
        {
            const ushort* sh = &Wthi[srow * K + k0 + skq];
            const ushort* sl = &Wtlo[srow * K + k0 + skq];
            *reinterpret_cast<uint4*>(&Bhi[srow][skq])     = *reinterpret_cast<const uint4*>(sh);
            *reinterpret_cast<uint4*>(&Bhi[srow][skq + 8]) = *reinterpret_cast<const uint4*>(sh + 8);
            *reinterpret_cast<uint4*>(&Blo[srow][skq])     = *reinterpret_cast<const uint4*>(sl);
            *reinterpret_cast<uint4*>(&Blo[srow][skq + 8]) = *reinterpret_cast<const uint4*>(sl + 8);
        }
        __syncthreads();
        short8 ah[4], al[4];
#pragma unroll
        for (int m = 0; m < 4; ++m) {
            ah[m] = *reinterpret_cast<const short8*>(&Ahi[wr + m * 16 + li][kb]);
            al[m] = *reinterpret_cast<const short8*>(&Alo[wr + m * 16 + li][kb]);
        }
#pragma unroll
        for (int n = 0; n < 4; ++n) {
            const short8 bh = *reinterpret_cast<const short8*>(&Bhi[wc + n * 16 + li][kb]);
            const short8 bl = *reinterpret_cast<const short8*>(&Blo[wc + n * 16 + li][kb]);
#pragma unroll
            for (int m = 0; m < 4; ++m) {
                acc[m][n] = __builtin_amdgcn_mfma_f32_16x16x32_bf16(ah[m], bh, acc[m][n], 0, 0, 0);
                acc[m][n] = __builtin_amdgcn_mfma_f32_16x16x32_bf16(ah[m], bl, acc[m][n], 0, 0, 0);
                acc[m][n] = __builtin_amdgcn_mfma_f32_16x16x32_bf16(al[m], bh, acc[m][n], 0, 0, 0);
            }
        }
        __syncthreads();
    }
    const int rbase = (lane >> 4) << 2;
#pragma unroll
    for (int m = 0; m < 4; ++m) {
        const int gr0 = row0 + wr + m * 16 + rbase;
#pragma unroll
        for (int r = 0; r < 4; ++r) {
            const int grow = gr0 + r;
            if (grow < M) {
                const float dv = dis[grow];
#pragma unroll
                for (int n = 0; n < 4; ++n) {
                    Hs[(size_t)grow * 128 + wc + n * 16 + li] = acc[m][n][r] * dv;
                }
            }
        }
    }
}

// ---------------------------------------------------------------- gather: 1 wave/node, float2/lane
// AGG[n] = b + dis[n] * (Hs[n] + sum_{s in in(n)} Hs[s])       (Hs pre-scaled by dis)
// POOL variant: skip AGG write; relu + per-block reduce + atomicAdd into pooled.
template <bool POOL>
__global__ __launch_bounds__(256) void gather_kernel(const int* __restrict__ rowptr,
                                                     const int* __restrict__ csr,
                                                     const float* __restrict__ Hs,
                                                     const float* __restrict__ dis,
                                                     const float* __restrict__ b,
                                                     float* __restrict__ AGG,
                                                     const int* __restrict__ batch,
                                                     float* __restrict__ pooled) {
    const int wave = threadIdx.x >> 6;
    const int lane = threadIdx.x & 63;
    const int node = blockIdx.x * 4 + wave;
    const int f2 = lane * 2;
    const int beg = rowptr[node];
    const int end = rowptr[node + 1];

    float2 acc = *reinterpret_cast<const float2*>(&Hs[(size_t)node * 128 + f2]);  // self
    int i = beg;
    for (; i + 4 <= end; i += 4) {
        const int s0 = csr[i], s1 = csr[i + 1], s2 = csr[i + 2], s3 = csr[i + 3];
        const float2 v0 = *reinterpret_cast<const float2*>(&Hs[(size_t)s0 * 128 + f2]);
        const float2 v1 = *reinterpret_cast<const float2*>(&Hs[(size_t)s1 * 128 + f2]);
        const float2 v2 = *reinterpret_cast<const float2*>(&Hs[(size_t)s2 * 128 + f2]);
        const float2 v3 = *reinterpret_cast<const float2*>(&Hs[(size_t)s3 * 128 + f2]);
        acc.x += (v0.x + v1.x) + (v2.x + v3.x);
        acc.y += (v0.y + v1.y) + (v2.y + v3.y);
    }
    for (; i < end; ++i) {
        const int s = csr[i];
        const float2 v = *reinterpret_cast<const float2*>(&Hs[(size_t)s * 128 + f2]);
        acc.x += v.x;
        acc.y += v.y;
    }
    const float d = dis[node];
    float2 o;
    o.x = fmaf(acc.x, d, b[f2]);
    o.y = fmaf(acc.y, d, b[f2 + 1]);

    if (!POOL) {
        *reinterpret_cast<float2*>(&AGG[(size_t)node * 128 + f2]) = o;
    } else {
        o.x = fmaxf(o.x, 0.f);
        o.y = fmaxf(o.y, 0.f);
        __shared__ float part[4][128];
        __shared__ int gs[4];
        const int g = batch[node];
        if (lane == 0) gs[wave] = g;
        part[wave][f2] = o.x;
        part[wave][f2 + 1] = o.y;
        __syncthreads();
        if (gs[0] == gs[1] && gs[1] == gs[2] && gs[2] == gs[3]) {
            if (threadIdx.x < 128) {
                const float s = (part[0][threadIdx.x] + part[1][threadIdx.x]) +
                                (part[2][threadIdx.x] + part[3][threadIdx.x]);
                atomicAdd(&pooled[gs[0] * HID + threadIdx.x], s);
            }
        } else {
            atomicAdd(&pooled[g * HID + f2], o.x);
            atomicAdd(&pooled[g * HID + f2 + 1], o.y);
        }
    }
}

// ---------------------------------------------------------------- pool stage 2: divide by counts
__global__ __launch_bounds__(128) void pooldiv_kernel(const int* __restrict__ batch,
                                                      float* __restrict__ pooled, int n) {
    const int g = blockIdx.x;
    int lo = 0, hi = n;
    while (lo < hi) { int mid = (lo + hi) >> 1; if (batch[mid] < g) lo = mid + 1; else hi = mid; }
    const int start = lo;
    hi = n;
    while (lo < hi) { int mid = (lo + hi) >> 1; if (batch[mid] < g + 1) lo = mid + 1; else hi = mid; }
    const float cnt = (float)(lo - start);
    pooled[g * HID + threadIdx.x] /= fmaxf(cnt, 1.f);
}

// ---------------------------------------------------------------- MLP head
__global__ __launch_bounds__(256) void mlp_kernel(const float* __restrict__ pooled,
                                                  const float* __restrict__ Wm1,
                                                  const float* __restrict__ bm1,
                                                  const float* __restrict__ Wm2,
                                                  const float* __restrict__ bm2,
                                                  float* __restrict__ out) {
    __shared__ float P[N_GRAPHS][HID];
    __shared__ float Wl[HID][MLP_HID];
    const int tid = threadIdx.x;
    for (int i = tid; i < N_GRAPHS * HID; i += 256) P[i >> 7][i & 127] = pooled[i];
    for (int i = tid; i < HID * MLP_HID; i += 256) Wl[i >> 6][i & 63] = Wm1[i];
    __syncthreads();
    const int g = tid >> 2;
    const int jb = tid & 3;
    float part = 0.f;
#pragma unroll
    for (int jj = 0; jj < 16; ++jj) {
        const int j = jb * 16 + jj;
        float z = bm1[j];
        for (int k = 0; k < HID; ++k) z = fmaf(P[g][k], Wl[k][j], z);
        z = fmaxf(z, 0.f);
        part = fmaf(z, Wm2[j], part);
    }
    part += __shfl_xor(part, 1);
    part += __shfl_xor(part, 2);
    if (jb == 0) out[g] = part + bm2[0];
}

extern "C" void kernel_launch(void* const* d_in, const int* in_sizes, int n_in,
                              void* d_out, int out_size, void* d_ws, size_t ws_size,
                              hipStream_t stream) {
    const float* x   = (const float*)d_in[0];
    const int*   ei  = (const int*)d_in[1];
    const int*   bat = (const int*)d_in[2];
    const float* W1  = (const float*)d_in[3];
    const float* b1  = (const float*)d_in[4];
    const float* W2  = (const float*)d_in[5];
    const float* b2  = (const float*)d_in[6];
    const float* W3  = (const float*)d_in[7];
    const float* b3  = (const float*)d_in[8];
    const float* Wm1 = (const float*)d_in[9];
    const float* bm1 = (const float*)d_in[10];
    const float* Wm2 = (const float*)d_in[11];
    const float* bm2 = (const float*)d_in[12];
    float* out = (float*)d_out;

    int*   cnt    = (int*)d_ws;                 // 50000
    int*   cursor = cnt + 50048;                // 50000
    int*   rowptr = cursor + 50048;             // 50001
    int*   csr    = rowptr + 50056;             // 800000
    int*   bsum   = csr + 800000;               // 256
    int*   boff   = bsum + 256;                 // 256
    float* dis    = (float*)(boff + 256);       // 50000
    float* H      = dis + 50048;                // 6.4M  (Hs: dis-prescaled)
    float* AGG    = H + N_NODES * HID;          // 6.4M
    float* pooled = AGG + N_NODES * HID;        // 8192
    ushort* wt1hi = (ushort*)(pooled + 8192);
    ushort* wt1lo = wt1hi + IN_DIM * HID;
    ushort* wt2hi = wt1lo + IN_DIM * HID;
    ushort* wt2lo = wt2hi + HID * HID;
    ushort* wt3hi = wt2lo + HID * HID;
    ushort* wt3lo = wt3hi + HID * HID;

    hipMemsetAsync(cnt, 0, N_NODES * sizeof(int), stream);
    hipMemsetAsync(pooled, 0, N_GRAPHS * HID * sizeof(float), stream);

    count_kernel<<<(N_EDGES + 255) / 256, 256, 0, stream>>>(ei + N_EDGES, cnt, N_EDGES);
    bsum_kernel<<<SCAN_BLOCKS, 256, 0, stream>>>(cnt, bsum);
    bscan_kernel<<<1, 256, 0, stream>>>(bsum, boff, rowptr);
    final_scan_kernel<<<SCAN_BLOCKS, 256, 0, stream>>>(cnt, boff, rowptr, cursor, dis);
    fill_kernel<<<(N_EDGES + 255) / 256, 256, 0, stream>>>(ei, cursor, csr, N_EDGES);

    wsplit_kernel<<<(IN_DIM * HID + 255) / 256, 256, 0, stream>>>(
        W1, W2, W3, wt1hi, wt1lo, wt2hi, wt2lo, wt3hi, wt3lo);

    // layer 1
    gemm_mfma_kernel<IN_DIM, false><<<GEMM_BLOCKS, 256, 0, stream>>>(x, wt1hi, wt1lo, dis, H, N_NODES);
    gather_kernel<false><<<GATHER_BLOCKS, 256, 0, stream>>>(rowptr, csr, H, dis, b1, AGG, bat, pooled);
    // layer 2
    gemm_mfma_kernel<HID, true><<<GEMM_BLOCKS, 256, 0, stream>>>(AGG, wt2hi, wt2lo, dis, H, N_NODES);
    gather_kernel<false><<<GATHER_BLOCKS, 256, 0, stream>>>(rowptr, csr, H, dis, b2, AGG, bat, pooled);
    // layer 3
    gemm_mfma_kernel<HID, true><<<GEMM_BLOCKS, 256, 0, stream>>>(AGG, wt3hi, wt3lo, dis, H, N_NODES);
    gather_kernel<true><<<GATHER_BLOCKS, 256, 0, stream>>>(rowptr, csr, H, dis, b3, AGG, bat, pooled);

    pooldiv_kernel<<<N_GRAPHS, 128, 0, stream>>>(bat, pooled, N_NODES);
    mlp_kernel<<<1, 256, 0, stream>>>(pooled, Wm1, bm1, Wm2, bm2, out);
}

// Round 8
// 514.233 us; speedup vs baseline: 8.6981x; 1.0167x over previous
//
#include <hip/hip_runtime.h>
#include <hip/hip_bf16.h>

#define N_NODES 50000
#define N_EDGES 800000
#define N_GRAPHS 64
#define IN_DIM 384
#define HID 128
#define MLP_HID 64

#define SCAN_BLOCKS ((N_NODES + 255) / 256)   // 196
#define GEMM_BLOCKS ((N_NODES + 127) / 128)   // 391
#define GATHER_BLOCKS (N_NODES / 4)           // 12500 (4 waves/block, 1 node/wave)

typedef __attribute__((ext_vector_type(8))) short short8;
typedef __attribute__((ext_vector_type(4))) float f32x4;
typedef unsigned int u32;

// ---------------------------------------------------------------- degree count (int)
__global__ __launch_bounds__(256) void count_kernel(const int* __restrict__ dst,
                                                    int* __restrict__ cnt, int E) {
    int t = blockIdx.x * 256 + threadIdx.x;
    if (t < E) atomicAdd(&cnt[dst[t]], 1);
}

// ---------------------------------------------------------------- scan pass 1: block sums
__global__ __launch_bounds__(256) void bsum_kernel(const int* __restrict__ cnt,
                                                   int* __restrict__ bsum) {
    __shared__ int sh[256];
    const int t = threadIdx.x;
    const int i = blockIdx.x * 256 + t;
    sh[t] = (i < N_NODES) ? cnt[i] : 0;
    __syncthreads();
#pragma unroll
    for (int off = 128; off > 0; off >>= 1) {
        if (t < off) sh[t] += sh[t + off];
        __syncthreads();
    }
    if (t == 0) bsum[blockIdx.x] = sh[0];
}

// ---------------------------------------------------------------- scan pass 2: scan block sums
__global__ __launch_bounds__(256) void bscan_kernel(const int* __restrict__ bsum,
                                                    int* __restrict__ boff,
                                                    int* __restrict__ rowptr) {
    __shared__ int sh[256];
    const int t = threadIdx.x;
    int v = (t < SCAN_BLOCKS) ? bsum[t] : 0;
    sh[t] = v;
    __syncthreads();
#pragma unroll
    for (int off = 1; off < 256; off <<= 1) {
        int u = 0;
        if (t >= off) u = sh[t - off];
        __syncthreads();
        if (t >= off) sh[t] += u;
        __syncthreads();
    }
    if (t < SCAN_BLOCKS) boff[t] = sh[t] - v;   // exclusive
    if (t == 255) rowptr[N_NODES] = sh[255];    // total
}

// ---------------------------------------------------------------- scan pass 3: final
__global__ __launch_bounds__(256) void final_scan_kernel(const int* __restrict__ cnt,
                                                         const int* __restrict__ boff,
                                                         int* __restrict__ rowptr,
                                                         int* __restrict__ cursor,
                                                         float* __restrict__ dis) {
    __shared__ int sh[256];
    const int t = threadIdx.x;
    const int i = blockIdx.x * 256 + t;
    const int c = (i < N_NODES) ? cnt[i] : 0;
    sh[t] = c;
    __syncthreads();
#pragma unroll
    for (int off = 1; off < 256; off <<= 1) {
        int u = 0;
        if (t >= off) u = sh[t - off];
        __syncthreads();
        if (t >= off) sh[t] += u;
        __syncthreads();
    }
    if (i < N_NODES) {
        const int pos = boff[blockIdx.x] + sh[t] - c;   // exclusive prefix
        rowptr[i] = pos;
        cursor[i] = pos;
        dis[i] = rsqrtf((float)c + 1.0f);
    }
}

// ---------------------------------------------------------------- CSR fill
__global__ __launch_bounds__(256) void fill_kernel(const int* __restrict__ ei,
                                                   int* __restrict__ cursor,
                                                   int* __restrict__ csr, int E) {
    int e = blockIdx.x * 256 + threadIdx.x;
    if (e >= E) return;
    int s = ei[e];
    int d = ei[E + e];
    int pos = atomicAdd(&cursor[d], 1);
    csr[pos] = s;
}

// ---------------------------------------------------------------- W split (all 3 weights, one dispatch)
__device__ __forceinline__ void wsplit_one(const float* W, ushort* hi, ushort* lo,
                                           int K, int t) {
    const int k = t >> 7;
    const int c = t & 127;
    const float f = W[t];
    const u32 u = __float_as_uint(f);
    const u32 h = u & 0xFFFF0000u;
    const float lf = f - __uint_as_float(h);
    hi[c * K + k] = (ushort)(u >> 16);
    lo[c * K + k] = (ushort)(__float_as_uint(lf) >> 16);
}

__global__ __launch_bounds__(256) void wsplit_kernel(const float* __restrict__ W1,
                                                     const float* __restrict__ W2,
                                                     const float* __restrict__ W3,
                                                     ushort* __restrict__ w1hi, ushort* __restrict__ w1lo,
                                                     ushort* __restrict__ w2hi, ushort* __restrict__ w2lo,
                                                     ushort* __restrict__ w3hi, ushort* __restrict__ w3lo) {
    int t = blockIdx.x * 256 + threadIdx.x;
    if (t < IN_DIM * HID) wsplit_one(W1, w1hi, w1lo, IN_DIM, t);
    if (t < HID * HID) {
        wsplit_one(W2, w2hi, w2lo, HID, t);
        wsplit_one(W3, w3hi, w3lo, HID, t);
    }
}

// ---------------------------------------------------------------- MFMA split-bf16 GEMM
// Hs[M,128] = ((relu?)X[M,K] @ W[K,128]) * dis[row]
template <int K, bool RELU_IN>
__global__ __launch_bounds__(256) void gemm_mfma_kernel(const float* __restrict__ X,
                                                        const ushort* __restrict__ Wthi,
                                                        const ushort* __restrict__ Wtlo,
                                                        const float* __restrict__ dis,
                                                        float* __restrict__ Hs, int M) {
    __shared__ ushort Ahi[128][40];
    __shared__ ushort Alo[128][40];
    __shared__ ushort Bhi[128][40];
    __shared__ ushort Blo[128][40];

    const int tid = threadIdx.x;
    const int row0 = blockIdx.x * 128;

    const int srow = tid >> 1;
    const int skq  = (tid & 1) << 4;

    const int lane = tid & 63;
    const int wave = tid >> 6;
    const int wr = (wave >> 1) * 64;
    const int wc = (wave & 1) * 64;
    const int li = lane & 15;
    const int kb = (lane >> 4) << 3;

    f32x4 acc[4][4];
#pragma unroll
    for (int m = 0; m < 4; ++m)
#pragma unroll
        for (int n = 0; n < 4; ++n) acc[m][n] = (f32x4){0.f, 0.f, 0.f, 0.f};

    for (int k0 = 0; k0 < K; k0 += 32) {
        {
            const int gr = row0 + srow;
            const float* src = &X[(size_t)(gr < M ? gr : (M - 1)) * K + k0 + skq];
            float f[16];
            *reinterpret_cast<float4*>(f)      = *reinterpret_cast<const float4*>(src);
            *reinterpret_cast<float4*>(f + 4)  = *reinterpret_cast<const float4*>(src + 4);
            *reinterpret_cast<float4*>(f + 8)  = *reinterpret_cast<const float4*>(src + 8);
            *reinterpret_cast<float4*>(f + 12) = *reinterpret_cast<const float4*>(src + 12);
            u32 hp[8], lp[8];
#pragma unroll
            for (int i = 0; i < 8; ++i) {
                float f0 = f[2 * i], f1 = f[2 * i + 1];
                if (RELU_IN) { f0 = fmaxf(f0, 0.f); f1 = fmaxf(f1, 0.f); }
                const u32 u0 = __float_as_uint(f0), u1 = __float_as_uint(f1);
                const u32 h0 = u0 & 0xFFFF0000u, h1 = u1 & 0xFFFF0000u;
                const float l0 = f0 - __uint_as_float(h0);
                const float l1 = f1 - __uint_as_float(h1);
                hp[i] = (h0 >> 16) | h1;
                lp[i] = (__float_as_uint(l0) >> 16) | (__float_as_uint(l1) & 0xFFFF0000u);
            }
            u32* dh = (u32*)&Ahi[srow][skq];
            u32* dl = (u32*)&Alo[srow][skq];
            *reinterpret_cast<uint4*>(dh)     = make_uint4(hp[0], hp[1], hp[2], hp[3]);
            *reinterpret_cast<uint4*>(dh + 4) = make_uint4(hp[4], hp[5], hp[6], hp[7]);
            *reinterpret_cast<uint4*>(dl)     = make_uint4(lp[0], lp[1], lp[2], lp[3]);
            *reinterpret_cast<uint4*>(dl + 4) = make_uint4(lp[4], lp[5], lp[6], lp[7]);
        }
        {
            const ushort* sh = &Wthi[srow * K + k0 + skq];
            const ushort* sl = &Wtlo[srow * K + k0 + skq];
            *reinterpret_cast<uint4*>(&Bhi[srow][skq])     = *reinterpret_cast<const uint4*>(sh);
            *reinterpret_cast<uint4*>(&Bhi[srow][skq + 8]) = *reinterpret_cast<const uint4*>(sh + 8);
            *reinterpret_cast<uint4*>(&Blo[srow][skq])     = *reinterpret_cast<const uint4*>(sl);
            *reinterpret_cast<uint4*>(&Blo[srow][skq + 8]) = *reinterpret_cast<const uint4*>(sl + 8);
        }
        __syncthreads();
        short8 ah[4], al[4];
#pragma unroll
        for (int m = 0; m < 4; ++m) {
            ah[m] = *reinterpret_cast<const short8*>(&Ahi[wr + m * 16 + li][kb]);
            al[m] = *reinterpret_cast<const short8*>(&Alo[wr + m * 16 + li][kb]);
        }
#pragma unroll
        for (int n = 0; n < 4; ++n) {
            const short8 bh = *reinterpret_cast<const short8*>(&Bhi[wc + n * 16 + li][kb]);
            const short8 bl = *reinterpret_cast<const short8*>(&Blo[wc + n * 16 + li][kb]);
#pragma unroll
            for (int m = 0; m < 4; ++m) {
                acc[m][n] = __builtin_amdgcn_mfma_f32_16x16x32_bf16(ah[m], bh, acc[m][n], 0, 0, 0);
                acc[m][n] = __builtin_amdgcn_mfma_f32_16x16x32_bf16(ah[m], bl, acc[m][n], 0, 0, 0);
                acc[m][n] = __builtin_amdgcn_mfma_f32_16x16x32_bf16(al[m], bh, acc[m][n], 0, 0, 0);
            }
        }
        __syncthreads();
    }
    const int rbase = (lane >> 4) << 2;
#pragma unroll
    for (int m = 0; m < 4; ++m) {
        const int gr0 = row0 + wr + m * 16 + rbase;
#pragma unroll
        for (int r = 0; r < 4; ++r) {
            const int grow = gr0 + r;
            if (grow < M) {
                const float dv = dis[grow];
#pragma unroll
                for (int n = 0; n < 4; ++n) {
                    Hs[(size_t)grow * 128 + wc + n * 16 + li] = acc[m][n][r] * dv;
                }
            }
        }
    }
}

// ---------------------------------------------------------------- gather: 1 wave/node
// Paired-row loads: lane<32 handles even edges, lane>=32 odd edges, float4/lane
// (1KB = 2 rows per instruction, 8 rows in flight). csr indices preloaded
// coalesced (64/chunk) and broadcast via shfl -> no per-iter index dependency.
// AGG[n] = b + dis[n] * (Hs[n] + sum Hs[src])      (Hs pre-scaled by dis)
template <bool POOL>
__global__ __launch_bounds__(256) void gather_kernel(const int* __restrict__ rowptr,
                                                     const int* __restrict__ csr,
                                                     const float* __restrict__ Hs,
                                                     const float* __restrict__ dis,
                                                     const float* __restrict__ b,
                                                     float* __restrict__ AGG,
                                                     const int* __restrict__ batch,
                                                     float* __restrict__ pooled) {
    const int wave = threadIdx.x >> 6;
    const int lane = threadIdx.x & 63;
    const int half = lane >> 5;
    const int fl = (lane & 31) << 2;      // feature base (float4)
    const int node = blockIdx.x * 4 + wave;
    const int beg = rowptr[node];
    const int end = rowptr[node + 1];

    float4 acc = make_float4(0.f, 0.f, 0.f, 0.f);
    if (half == 0) acc = *reinterpret_cast<const float4*>(&Hs[(size_t)node * 128 + fl]);  // self

    for (int cbeg = beg; cbeg < end; cbeg += 64) {
        const int cnt = min(cbeg + 64, end) - cbeg;
        const int myidx = (cbeg + lane < end) ? csr[cbeg + lane] : 0;
        int j = 0;
        for (; j + 8 <= cnt; j += 8) {
            const int s0 = __shfl(myidx, j + 0), s1 = __shfl(myidx, j + 1);
            const int s2 = __shfl(myidx, j + 2), s3 = __shfl(myidx, j + 3);
            const int s4 = __shfl(myidx, j + 4), s5 = __shfl(myidx, j + 5);
            const int s6 = __shfl(myidx, j + 6), s7 = __shfl(myidx, j + 7);
            const size_t ra = (size_t)(half ? s1 : s0) * 128 + fl;
            const size_t rb = (size_t)(half ? s3 : s2) * 128 + fl;
            const size_t rc = (size_t)(half ? s5 : s4) * 128 + fl;
            const size_t rd = (size_t)(half ? s7 : s6) * 128 + fl;
            const float4 v0 = *reinterpret_cast<const float4*>(&Hs[ra]);
            const float4 v1 = *reinterpret_cast<const float4*>(&Hs[rb]);
            const float4 v2 = *reinterpret_cast<const float4*>(&Hs[rc]);
            const float4 v3 = *reinterpret_cast<const float4*>(&Hs[rd]);
            acc.x += (v0.x + v1.x) + (v2.x + v3.x);
            acc.y += (v0.y + v1.y) + (v2.y + v3.y);
            acc.z += (v0.z + v1.z) + (v2.z + v3.z);
            acc.w += (v0.w + v1.w) + (v2.w + v3.w);
        }
        for (; j + 2 <= cnt; j += 2) {
            const int s0 = __shfl(myidx, j), s1 = __shfl(myidx, j + 1);
            const float4 v = *reinterpret_cast<const float4*>(&Hs[(size_t)(half ? s1 : s0) * 128 + fl]);
            acc.x += v.x; acc.y += v.y; acc.z += v.z; acc.w += v.w;
        }
        if (j < cnt) {
            const int s0 = __shfl(myidx, j);
            if (half == 0) {
                const float4 v = *reinterpret_cast<const float4*>(&Hs[(size_t)s0 * 128 + fl]);
                acc.x += v.x; acc.y += v.y; acc.z += v.z; acc.w += v.w;
            }
        }
    }
    // cross-half reduce: lane l and l+32 hold same features
    acc.x += __shfl_xor(acc.x, 32);
    acc.y += __shfl_xor(acc.y, 32);
    acc.z += __shfl_xor(acc.z, 32);
    acc.w += __shfl_xor(acc.w, 32);

    if (!POOL) {
        if (half == 0) {
            const float d = dis[node];
            const float4 bb = *reinterpret_cast<const float4*>(&b[fl]);
            float4 o;
            o.x = fmaf(acc.x, d, bb.x);
            o.y = fmaf(acc.y, d, bb.y);
            o.z = fmaf(acc.z, d, bb.z);
            o.w = fmaf(acc.w, d, bb.w);
            *reinterpret_cast<float4*>(&AGG[(size_t)node * 128 + fl]) = o;
        }
    } else {
        __shared__ float part[4][128];
        __shared__ int gs[4];
        const int g = batch[node];
        if (lane == 0) gs[wave] = g;
        if (half == 0) {
            const float d = dis[node];
            const float4 bb = *reinterpret_cast<const float4*>(&b[fl]);
            float4 o;
            o.x = fmaxf(fmaf(acc.x, d, bb.x), 0.f);
            o.y = fmaxf(fmaf(acc.y, d, bb.y), 0.f);
            o.z = fmaxf(fmaf(acc.z, d, bb.z), 0.f);
            o.w = fmaxf(fmaf(acc.w, d, bb.w), 0.f);
            *reinterpret_cast<float4*>(&part[wave][fl]) = o;
        }
        __syncthreads();
        if (gs[0] == gs[1] && gs[1] == gs[2] && gs[2] == gs[3]) {
            if (threadIdx.x < 128) {
                const float s = (part[0][threadIdx.x] + part[1][threadIdx.x]) +
                                (part[2][threadIdx.x] + part[3][threadIdx.x]);
                atomicAdd(&pooled[gs[0] * HID + threadIdx.x], s);
            }
        } else if (half == 0) {
            atomicAdd(&pooled[g * HID + fl],     part[wave][fl]);
            atomicAdd(&pooled[g * HID + fl + 1], part[wave][fl + 1]);
            atomicAdd(&pooled[g * HID + fl + 2], part[wave][fl + 2]);
            atomicAdd(&pooled[g * HID + fl + 3], part[wave][fl + 3]);
        }
    }
}

// ---------------------------------------------------------------- pool stage 2: divide by counts
__global__ __launch_bounds__(128) void pooldiv_kernel(const int* __restrict__ batch,
                                                      float* __restrict__ pooled, int n) {
    const int g = blockIdx.x;
    int lo = 0, hi = n;
    while (lo < hi) { int mid = (lo + hi) >> 1; if (batch[mid] < g) lo = mid + 1; else hi = mid; }
    const int start = lo;
    hi = n;
    while (lo < hi) { int mid = (lo + hi) >> 1; if (batch[mid] < g + 1) lo = mid + 1; else hi = mid; }
    const float cnt = (float)(lo - start);
    pooled[g * HID + threadIdx.x] /= fmaxf(cnt, 1.f);
}

// ---------------------------------------------------------------- MLP head
__global__ __launch_bounds__(256) void mlp_kernel(const float* __restrict__ pooled,
                                                  const float* __restrict__ Wm1,
                                                  const float* __restrict__ bm1,
                                                  const float* __restrict__ Wm2,
                                                  const float* __restrict__ bm2,
                                                  float* __restrict__ out) {
    __shared__ float P[N_GRAPHS][HID];
    __shared__ float Wl[HID][MLP_HID];
    const int tid = threadIdx.x;
    for (int i = tid; i < N_GRAPHS * HID; i += 256) P[i >> 7][i & 127] = pooled[i];
    for (int i = tid; i < HID * MLP_HID; i += 256) Wl[i >> 6][i & 63] = Wm1[i];
    __syncthreads();
    const int g = tid >> 2;
    const int jb = tid & 3;
    float part = 0.f;
#pragma unroll
    for (int jj = 0; jj < 16; ++jj) {
        const int j = jb * 16 + jj;
        float z = bm1[j];
        for (int k = 0; k < HID; ++k) z = fmaf(P[g][k], Wl[k][j], z);
        z = fmaxf(z, 0.f);
        part = fmaf(z, Wm2[j], part);
    }
    part += __shfl_xor(part, 1);
    part += __shfl_xor(part, 2);
    if (jb == 0) out[g] = part + bm2[0];
}

extern "C" void kernel_launch(void* const* d_in, const int* in_sizes, int n_in,
                              void* d_out, int out_size, void* d_ws, size_t ws_size,
                              hipStream_t stream) {
    const float* x   = (const float*)d_in[0];
    const int*   ei  = (const int*)d_in[1];
    const int*   bat = (const int*)d_in[2];
    const float* W1  = (const float*)d_in[3];
    const float* b1  = (const float*)d_in[4];
    const float* W2  = (const float*)d_in[5];
    const float* b2  = (const float*)d_in[6];
    const float* W3  = (const float*)d_in[7];
    const float* b3  = (const float*)d_in[8];
    const float* Wm1 = (const float*)d_in[9];
    const float* bm1 = (const float*)d_in[10];
    const float* Wm2 = (const float*)d_in[11];
    const float* bm2 = (const float*)d_in[12];
    float* out = (float*)d_out;

    int*   cnt    = (int*)d_ws;                 // 50000
    int*   cursor = cnt + 50048;                // 50000
    int*   rowptr = cursor + 50048;             // 50001
    int*   csr    = rowptr + 50056;             // 800000
    int*   bsum   = csr + 800000;               // 256
    int*   boff   = bsum + 256;                 // 256
    float* dis    = (float*)(boff + 256);       // 50000
    float* H      = dis + 50048;                // 6.4M  (Hs: dis-prescaled)
    float* AGG    = H + N_NODES * HID;          // 6.4M
    float* pooled = AGG + N_NODES * HID;        // 8192
    ushort* wt1hi = (ushort*)(pooled + 8192);
    ushort* wt1lo = wt1hi + IN_DIM * HID;
    ushort* wt2hi = wt1lo + IN_DIM * HID;
    ushort* wt2lo = wt2hi + HID * HID;
    ushort* wt3hi = wt2lo + HID * HID;
    ushort* wt3lo = wt3hi + HID * HID;

    hipMemsetAsync(cnt, 0, N_NODES * sizeof(int), stream);
    hipMemsetAsync(pooled, 0, N_GRAPHS * HID * sizeof(float), stream);

    count_kernel<<<(N_EDGES + 255) / 256, 256, 0, stream>>>(ei + N_EDGES, cnt, N_EDGES);
    bsum_kernel<<<SCAN_BLOCKS, 256, 0, stream>>>(cnt, bsum);
    bscan_kernel<<<1, 256, 0, stream>>>(bsum, boff, rowptr);
    final_scan_kernel<<<SCAN_BLOCKS, 256, 0, stream>>>(cnt, boff, rowptr, cursor, dis);
    fill_kernel<<<(N_EDGES + 255) / 256, 256, 0, stream>>>(ei, cursor, csr, N_EDGES);

    wsplit_kernel<<<(IN_DIM * HID + 255) / 256, 256, 0, stream>>>(
        W1, W2, W3, wt1hi, wt1lo, wt2hi, wt2lo, wt3hi, wt3lo);

    // layer 1
    gemm_mfma_kernel<IN_DIM, false><<<GEMM_BLOCKS, 256, 0, stream>>>(x, wt1hi, wt1lo, dis, H, N_NODES);
    gather_kernel<false><<<GATHER_BLOCKS, 256, 0, stream>>>(rowptr, csr, H, dis, b1, AGG, bat, pooled);
    // layer 2
    gemm_mfma_kernel<HID, true><<<GEMM_BLOCKS, 256, 0, stream>>>(AGG, wt2hi, wt2lo, dis, H, N_NODES);
    gather_kernel<false><<<GATHER_BLOCKS, 256, 0, stream>>>(rowptr, csr, H, dis, b2, AGG, bat, pooled);
    // layer 3
    gemm_mfma_kernel<HID, true><<<GEMM_BLOCKS, 256, 0, stream>>>(AGG, wt3hi, wt3lo, dis, H, N_NODES);
    gather_kernel<true><<<GATHER_BLOCKS, 256, 0, stream>>>(rowptr, csr, H, dis, b3, AGG, bat, pooled);

    pooldiv_kernel<<<N_GRAPHS, 128, 0, stream>>>(bat, pooled, N_NODES);
    mlp_kernel<<<1, 256, 0, stream>>>(pooled, Wm1, bm1, Wm2, bm2, out);
}